// Round 17
// baseline (434.195 us; speedup 1.0000x reference)
//
#include <hip/hip_runtime.h>

#define N_NODES 100000
#define N_EDGES 3200000
#define BN_EPS 1e-5f

#define BLK_NODES 128            // nodes per bin block
#define NBLK 782                 // ceil(100000/128)
#define CHUNK 4096               // edges per fill workgroup (782 wgs -> 3/CU)
#define NW ((N_EDGES + CHUNK - 1) / CHUNK)  // 782
#define BCAP 4480                // words per bin (mean 4094, ~6 sigma)
#define CUR_PAD 16               // ints per cursor -> 64B
#define NSLICE 32                // stat partial slices

typedef unsigned int uint;
typedef unsigned short ushort;
typedef _Float16 half_t;
typedef __attribute__((ext_vector_type(8))) _Float16 h8v;  // 8 f16 (4 VGPRs)
typedef __attribute__((ext_vector_type(4))) float f4v;     // MFMA C/D

__device__ inline float bf_lo(uint u) { return __uint_as_float(u << 16); }
__device__ inline float bf_hi(uint u) { return __uint_as_float(u & 0xffff0000u); }
__device__ inline float h_lo(uint u) {
    union { ushort s; half_t h; } r; r.s = (ushort)(u & 0xffffu); return (float)r.h;
}
__device__ inline float h_hi(uint u) {
    union { ushort s; half_t h; } r; r.s = (ushort)(u >> 16); return (float)r.h;
}
__device__ inline ushort f2bf(float a) {
    uint ua = __float_as_uint(a); ua += 0x7fffu + ((ua >> 16) & 1u);
    return (ushort)(ua >> 16);
}
__device__ inline ushort f2h(float a) {
    union { half_t h; ushort u; } r;
    r.h = (half_t)a;
    return r.u;
}
__device__ inline uint packh2(float a, float b) {
    return (uint)f2h(a) | ((uint)f2h(b) << 16);
}
__device__ inline h8v loadH(const ushort* p) {
    union { uint4 q; h8v f; } r;
    r.q = *(const uint4*)p;
    return r.f;
}
__device__ inline h8v loadHh(const half_t* p) {
    union { uint4 q; h8v f; } r;
    r.q = *(const uint4*)p;
    return r.f;
}
__device__ inline f4v mfma16(h8v a, h8v b, f4v c) {
    return __builtin_amdgcn_mfma_f32_16x16x32_f16(a, b, c, 0, 0, 0);
}

// ---------------------------------------------------------------------------
// Build h0 [N,16]: [x0, x1, emb[label][0..7], 0 x6]
__global__ __launch_bounds__(256) void k_h0(const float* __restrict__ x,
                                            const int* __restrict__ lab,
                                            const float* __restrict__ emb,
                                            float* __restrict__ h0, int n) {
    int i = blockIdx.x * blockDim.x + threadIdx.x;
    if (i >= n) return;
    float v[16];
    v[0] = x[2 * i];
    v[1] = x[2 * i + 1];
    int L = lab[i];
#pragma unroll
    for (int k = 0; k < 8; k++) v[2 + k] = emb[L * 8 + k];
#pragma unroll
    for (int k = 10; k < 16; k++) v[k] = 0.f;
    float4* o = (float4*)(h0 + (size_t)i * 16);
#pragma unroll
    for (int q = 0; q < 4; q++) {
        float4 t;
        t.x = v[4 * q]; t.y = v[4 * q + 1]; t.z = v[4 * q + 2]; t.w = v[4 * q + 3];
        o[q] = t;
    }
}

// ---------------------------------------------------------------------------
// Weight convert/transpose to f16: Wt[n][k] so B-frag reads are contiguous.
__global__ __launch_bounds__(256) void k_wcvt(const float* __restrict__ W1_0,
                                              const float* __restrict__ W2_0,
                                              const float* __restrict__ W1_s,
                                              const float* __restrict__ W2_s,
                                              ushort* __restrict__ W0t,
                                              ushort* __restrict__ W20t,
                                              ushort* __restrict__ Wst) {
    int t = threadIdx.x;
    for (int i = t; i < 64 * 32; i += 256) {       // W0t [64][32], K padded
        int n = i >> 5, k = i & 31;
        W0t[i] = (k < 10) ? f2h(W1_0[k * 64 + n]) : (ushort)0;
    }
    for (int i = t; i < 4096; i += 256) {          // W20t [64][64]
        int n = i >> 6, k = i & 63;
        W20t[i] = f2h(W2_0[k * 64 + n]);
    }
    for (int l = 0; l < 2; l++) {
        const float* w1 = W1_s + l * 4096;
        const float* w2 = W2_s + l * 4096;
        for (int i = t; i < 4096; i += 256) {
            int n = i >> 6, k = i & 63;
            Wst[l * 8192 + i] = f2h(w1[k * 64 + n]);
            Wst[l * 8192 + 4096 + i] = f2h(w2[k * 64 + n]);
        }
    }
}

// ---------------------------------------------------------------------------
// LDS-binned fill: count chunk into 782 bins, reserve contiguous runs
// (1 atomic per wg-bin), stream words into runs. CHUNK=4096 -> 782 wgs.
__global__ __launch_bounds__(256) void k_fill(const int* __restrict__ src,
                                              const int* __restrict__ dst,
                                              int* __restrict__ gcur,
                                              int* __restrict__ bucket) {
    __shared__ int cnt[NBLK];
    __shared__ int off[NBLK];
    int t = threadIdx.x;
    for (int b = t; b < NBLK; b += 256) cnt[b] = 0;
    __syncthreads();
    int my0 = blockIdx.x * CHUNK + t * (CHUNK / 256);
    const int PER = CHUNK / 256;  // 16 edges per thread
    for (int k = 0; k < PER; k += 4) {
        int e = my0 + k;
        if (e + 3 < N_EDGES) {
            int4 d4 = *(const int4*)(dst + e);
            atomicAdd(&cnt[d4.x >> 7], 1);
            atomicAdd(&cnt[d4.y >> 7], 1);
            atomicAdd(&cnt[d4.z >> 7], 1);
            atomicAdd(&cnt[d4.w >> 7], 1);
        } else {
#pragma unroll
            for (int kk = 0; kk < 4; kk++) {
                int ee = e + kk;
                if (ee < N_EDGES) atomicAdd(&cnt[dst[ee] >> 7], 1);
            }
        }
    }
    __syncthreads();
    for (int b = t; b < NBLK; b += 256) {
        int c = cnt[b];
        off[b] = (c > 0) ? atomicAdd(&gcur[b * CUR_PAD], c) : 0;
    }
    __syncthreads();
    for (int k = 0; k < PER; k += 4) {
        int e = my0 + k;
        if (e + 3 < N_EDGES) {
            int4 d4 = *(const int4*)(dst + e);
            int4 s4 = *(const int4*)(src + e);
            int dd[4] = {d4.x, d4.y, d4.z, d4.w};
            int ss[4] = {s4.x, s4.y, s4.z, s4.w};
#pragma unroll
            for (int kk = 0; kk < 4; kk++) {
                int b = dd[kk] >> 7;
                int p = atomicAdd(&off[b], 1);
                if (p < BCAP)
                    bucket[(size_t)b * BCAP + p] = ((dd[kk] & 127) << 17) | ss[kk];
            }
        } else {
#pragma unroll
            for (int kk = 0; kk < 4; kk++) {
                int ee = e + kk;
                if (ee < N_EDGES) {
                    int d = dst[ee], s = src[ee];
                    int b = d >> 7;
                    int p = atomicAdd(&off[b], 1);
                    if (p < BCAP)
                        bucket[(size_t)b * BCAP + p] = ((d & 127) << 17) | s;
                }
            }
        }
    }
}

// ---------------------------------------------------------------------------
// Per-block counting sort -> per-node-contiguous col2 + nodeoff = (start,deg)
__global__ __launch_bounds__(256) void k_sort(const int* __restrict__ gcur,
                                              const int* __restrict__ bucket,
                                              int* __restrict__ col2,
                                              int2* __restrict__ nodeoff, int n) {
    __shared__ int cnt[BLK_NODES];
    __shared__ int scn[BLK_NODES];
    __shared__ int cur[BLK_NODES];
    int t = threadIdx.x;
    int blk = blockIdx.x;
    if (t < BLK_NODES) cnt[t] = 0;
    __syncthreads();
    int cc = min(gcur[blk * CUR_PAD], BCAP);
    const int* bb = bucket + (size_t)blk * BCAP;
    for (int i = t; i < cc; i += 256) atomicAdd(&cnt[bb[i] >> 17], 1);
    __syncthreads();
    if (t < BLK_NODES) scn[t] = cnt[t];
    __syncthreads();
#pragma unroll
    for (int off = 1; off < BLK_NODES; off <<= 1) {
        int v = (t >= off && t < BLK_NODES) ? scn[t - off] : 0;
        __syncthreads();
        if (t < BLK_NODES) scn[t] += v;
        __syncthreads();
    }
    if (t < BLK_NODES) {
        int start = scn[t] - cnt[t];
        cur[t] = start;
        int node = blk * BLK_NODES + t;
        if (node < n) nodeoff[node] = int2{blk * BCAP + start, cnt[t]};
    }
    __syncthreads();
    int* out = col2 + (size_t)blk * BCAP;
    for (int i = t; i < cc; i += 256) {
        int w = bb[i];
        int p = atomicAdd(&cur[w >> 17], 1);
        out[p] = w & 0x1FFFF;
    }
}

// ---------------------------------------------------------------------------
// Layer 0: block = 4 waves = 64 nodes. Gather16 (2 nodes/wave x 8 rounds,
// depth-2 col pipeline) into wave-private f16 LDS, then f16 MFMA MLP + stats.
__global__ __launch_bounds__(256, 4) void k_layer0M(const float* __restrict__ h0,
                                                    const int2* __restrict__ nodeoff,
                                                    const int* __restrict__ col,
                                                    const float* __restrict__ epsp,
                                                    const ushort* __restrict__ W0t,
                                                    const float* __restrict__ b1,
                                                    const ushort* __restrict__ W20t,
                                                    const float* __restrict__ b2,
                                                    ushort* __restrict__ hraw,
                                                    float* __restrict__ part_out) {
    __shared__ half_t buf[4][16][72];   // comb (cols 0..31) then h1 (cols 0..63)
    int t = threadIdx.x, w = t >> 6, lane = t & 63;
    int base = blockIdx.x * 64 + w * 16;
    float ep = 1.f + *epsp;
    int hl = lane >> 5, l5 = lane & 31;
    int q = l5 & 3, g = l5 >> 2;  // 8 groups x 4 lanes per half
    const float4* h4 = (const float4*)h0;

    int nj = base + (lane & 15);
    int2 no2 = nodeoff[nj];  // padded past N
    int myStart = no2.x;
    int myDeg = (nj < N_NODES) ? no2.y : 0;

    int stC, dgC, mxC, wvC, wv2C;
    {
        stC = __shfl(myStart, hl, 64);
        dgC = __shfl(myDeg, hl, 64);
        int dA = __shfl(myDeg, 0, 64), dB = __shfl(myDeg, 1, 64);
        mxC = max(dA, dB);
        wvC = (dgC > 0) ? col[stC + min(l5, dgC - 1)] : 0;
        wv2C = (mxC > 32) ? ((dgC > 32) ? col[stC + min(32 + l5, dgC - 1)] : wvC) : 0;
    }

    for (int r = 0; r < 8; r++) {
        int stN = 0, dgN = 0, mxN = 0, wvN = 0, wv2N = 0;
        if (r < 7) {
            stN = __shfl(myStart, 2 * (r + 1) + hl, 64);
            dgN = __shfl(myDeg, 2 * (r + 1) + hl, 64);
            int dA = __shfl(myDeg, 2 * (r + 1), 64);
            int dB = __shfl(myDeg, 2 * (r + 1) + 1, 64);
            mxN = max(dA, dB);
            wvN = (dgN > 0) ? col[stN + min(l5, dgN - 1)] : 0;
            wv2N = (mxN > 32) ? ((dgN > 32) ? col[stN + min(32 + l5, dgN - 1)] : wvN) : 0;
        }
        int deg = dgC, mx = mxC;
        float ac[4] = {0.f, 0.f, 0.f, 0.f};
        if (mx > 0) {
            int idx[4];
#pragma unroll
            for (int i = 0; i < 4; i++) idx[i] = __shfl(wvC, (hl << 5) + g + 8 * i, 64);
            float4 rows[4];
#pragma unroll
            for (int i = 0; i < 4; i++) rows[i] = h4[(size_t)idx[i] * 4 + q];
#pragma unroll
            for (int i = 0; i < 4; i++) {
                float m = (g + 8 * i < deg) ? 1.f : 0.f;
                ac[0] = fmaf(m, rows[i].x, ac[0]);
                ac[1] = fmaf(m, rows[i].y, ac[1]);
                ac[2] = fmaf(m, rows[i].z, ac[2]);
                ac[3] = fmaf(m, rows[i].w, ac[3]);
            }
            if (mx > 32) {
                int idx2[4];
#pragma unroll
                for (int i = 0; i < 4; i++) idx2[i] = __shfl(wv2C, (hl << 5) + g + 8 * i, 64);
                float4 rows2[4];
#pragma unroll
                for (int i = 0; i < 4; i++) rows2[i] = h4[(size_t)idx2[i] * 4 + q];
#pragma unroll
                for (int i = 0; i < 4; i++) {
                    float m = (32 + g + 8 * i < deg) ? 1.f : 0.f;
                    ac[0] = fmaf(m, rows2[i].x, ac[0]);
                    ac[1] = fmaf(m, rows2[i].y, ac[1]);
                    ac[2] = fmaf(m, rows2[i].z, ac[2]);
                    ac[3] = fmaf(m, rows2[i].w, ac[3]);
                }
                for (int e = 64 + g; e < deg; e += 8) {
                    float4 v = h4[(size_t)col[stC + e] * 4 + q];
                    ac[0] += v.x; ac[1] += v.y; ac[2] += v.z; ac[3] += v.w;
                }
            }
        }
#pragma unroll
        for (int o = 4; o < 32; o <<= 1) {
#pragma unroll
            for (int k = 0; k < 4; k++) ac[k] += __shfl_xor(ac[k], o, 64);
        }
        int node = base + 2 * r + hl;
        bool valid = node < N_NODES;
        int nodeC = valid ? node : 0;
        float vm = valid ? ep : 0.f;
        float4 xi = h4[(size_t)nodeC * 4 + q];
        ac[0] = fmaf(vm, xi.x, ac[0]);
        ac[1] = fmaf(vm, xi.y, ac[1]);
        ac[2] = fmaf(vm, xi.z, ac[2]);
        ac[3] = fmaf(vm, xi.w, ac[3]);
        if (!valid) { ac[0] = ac[1] = ac[2] = ac[3] = 0.f; }
        if (g == 0) {
            int nl = 2 * r + hl;
            *(uint2*)&buf[w][nl][q * 4] = uint2{packh2(ac[0], ac[1]), packh2(ac[2], ac[3])};
            *(uint2*)&buf[w][nl][16 + q * 4] = uint2{0u, 0u};
        }
        stC = stN; dgC = dgN; mxC = mxN; wvC = wvN; wv2C = wv2N;
    }
    // ---- f16 MFMA MLP (wave-synchronous LDS; no barrier; buf aliased) ----
    int mr = lane & 15, kq = lane >> 4, nc = lane & 15;
    h8v A0 = loadHh(&buf[w][mr][kq * 8]);
#pragma unroll
    for (int nt = 0; nt < 4; nt++) {
        float bb = b1[nt * 16 + nc];
        f4v c = {bb, bb, bb, bb};
        c = mfma16(A0, loadH(W0t + (nt * 16 + nc) * 32 + kq * 8), c);
#pragma unroll
        for (int r2 = 0; r2 < 4; r2++)
            buf[w][kq * 4 + r2][nt * 16 + nc] = (half_t)fmaxf(c[r2], 0.f);
    }
    h8v P0 = loadHh(&buf[w][mr][kq * 8]);
    h8v P1 = loadHh(&buf[w][mr][32 + kq * 8]);
    float sA[4], sB[4];
#pragma unroll
    for (int nt = 0; nt < 4; nt++) { sA[nt] = 0.f; sB[nt] = 0.f; }
#pragma unroll
    for (int nt = 0; nt < 4; nt++) {
        float bb = b2[nt * 16 + nc];
        f4v c = {bb, bb, bb, bb};
        c = mfma16(P0, loadH(W20t + (nt * 16 + nc) * 64 + kq * 8), c);
        c = mfma16(P1, loadH(W20t + (nt * 16 + nc) * 64 + 32 + kq * 8), c);
#pragma unroll
        for (int r2 = 0; r2 < 4; r2++) {
            int node = base + kq * 4 + r2;
            float vv = fmaxf(c[r2], 0.f);
            if (node < N_NODES) {
                sA[nt] += vv;
                sB[nt] = fmaf(vv, vv, sB[nt]);
                hraw[(size_t)node * 64 + nt * 16 + nc] = f2h(vv);
            }
        }
    }
#pragma unroll
    for (int o = 16; o < 64; o <<= 1) {
#pragma unroll
        for (int nt = 0; nt < 4; nt++) {
            sA[nt] += __shfl_xor(sA[nt], o, 64);
            sB[nt] += __shfl_xor(sB[nt], o, 64);
        }
    }
    if (kq == 0) {
        float* pp = part_out + (blockIdx.x & (NSLICE - 1)) * 128;
#pragma unroll
        for (int nt = 0; nt < 4; nt++) {
            atomicAdd(&pp[nt * 16 + nc], sA[nt]);
            atomicAdd(&pp[64 + nt * 16 + nc], sB[nt]);
        }
    }
}

// ---------------------------------------------------------------------------
// Activation pass: act = bf16(relu(h*sc+sh)), h stored f16, BN from partials.
__global__ __launch_bounds__(256) void k_act(const ushort* __restrict__ hraw,
                                             const float* __restrict__ part,
                                             const float* __restrict__ gamma,
                                             const float* __restrict__ beta,
                                             ushort* __restrict__ act, float invn) {
    __shared__ float st[128];
    __shared__ float sc[64], sh[64];
    int t = threadIdx.x;
    if (t < 128) {
        float S = 0.f;
#pragma unroll 8
        for (int s = 0; s < NSLICE; s++) S += part[s * 128 + t];
        st[t] = S;
    }
    __syncthreads();
    if (t < 64) {
        float mu = st[t] * invn;
        float var = fmaxf(st[64 + t] * invn - mu * mu, 0.f);
        float s = gamma[t] * rsqrtf(var + BN_EPS);
        sc[t] = s;
        sh[t] = beta[t] - mu * s;
    }
    __syncthreads();
    int base = (blockIdx.x * 256 + t) * 4;
    int f0 = base & 63;
    uint2 hv = *(const uint2*)(hraw + base);
    float a0 = fmaxf(fmaf(h_lo(hv.x), sc[f0 + 0], sh[f0 + 0]), 0.f);
    float a1 = fmaxf(fmaf(h_hi(hv.x), sc[f0 + 1], sh[f0 + 1]), 0.f);
    float a2 = fmaxf(fmaf(h_lo(hv.y), sc[f0 + 2], sh[f0 + 2]), 0.f);
    float a3 = fmaxf(fmaf(h_hi(hv.y), sc[f0 + 3], sh[f0 + 3]), 0.f);
    uint2 o;
    o.x = (uint)f2bf(a0) | ((uint)f2bf(a1) << 16);
    o.y = (uint)f2bf(a2) | ((uint)f2bf(a3) << 16);
    *(uint2*)(act + base) = o;
}

// ---------------------------------------------------------------------------
// Layers 1/2: block = 4 waves = 64 nodes. Gather64 over pre-activated bf16
// (2 nodes/wave x 8 rounds, depth-2 col pipeline) into wave-private f16 LDS,
// then f16 MFMA MLP + stats + f16 store.
__global__ __launch_bounds__(256, 4) void k_layerM(const uint* __restrict__ actin,
                                                   const int2* __restrict__ nodeoff,
                                                   const int* __restrict__ col,
                                                   const float* __restrict__ epsp,
                                                   const ushort* __restrict__ W1t,
                                                   const float* __restrict__ b1,
                                                   const ushort* __restrict__ W2t,
                                                   const float* __restrict__ b2,
                                                   ushort* __restrict__ hraw,
                                                   float* __restrict__ part_out) {
    __shared__ half_t buf[4][16][72];   // comb then h1 (aliased, wave-private)
    int t = threadIdx.x, w = t >> 6, lane = t & 63;
    int base = blockIdx.x * 64 + w * 16;
    float ep = 1.f + *epsp;
    int hl = lane >> 5, l5 = lane & 31;
    int q = l5 & 7, g = l5 >> 3;  // 4 groups x 8 lanes per half
    const uint4* hb4 = (const uint4*)actin;

    int nj = base + (lane & 15);
    int2 no2 = nodeoff[nj];
    int myStart = no2.x;
    int myDeg = (nj < N_NODES) ? no2.y : 0;

    int stC, dgC, mxC, wvC, wv2C;
    {
        stC = __shfl(myStart, hl, 64);
        dgC = __shfl(myDeg, hl, 64);
        int dA = __shfl(myDeg, 0, 64), dB = __shfl(myDeg, 1, 64);
        mxC = max(dA, dB);
        wvC = (dgC > 0) ? col[stC + min(l5, dgC - 1)] : 0;
        wv2C = (mxC > 32) ? ((dgC > 32) ? col[stC + min(32 + l5, dgC - 1)] : wvC) : 0;
    }

    for (int r = 0; r < 8; r++) {
        int stN = 0, dgN = 0, mxN = 0, wvN = 0, wv2N = 0;
        if (r < 7) {
            stN = __shfl(myStart, 2 * (r + 1) + hl, 64);
            dgN = __shfl(myDeg, 2 * (r + 1) + hl, 64);
            int dA = __shfl(myDeg, 2 * (r + 1), 64);
            int dB = __shfl(myDeg, 2 * (r + 1) + 1, 64);
            mxN = max(dA, dB);
            wvN = (dgN > 0) ? col[stN + min(l5, dgN - 1)] : 0;
            wv2N = (mxN > 32) ? ((dgN > 32) ? col[stN + min(32 + l5, dgN - 1)] : wvN) : 0;
        }
        int deg = dgC, mx = mxC;
        float acc[8];
#pragma unroll
        for (int k = 0; k < 8; k++) acc[k] = 0.f;
        auto procm = [&](uint4 v, float m) {
            acc[0] = fmaf(m, bf_lo(v.x), acc[0]);
            acc[1] = fmaf(m, bf_hi(v.x), acc[1]);
            acc[2] = fmaf(m, bf_lo(v.y), acc[2]);
            acc[3] = fmaf(m, bf_hi(v.y), acc[3]);
            acc[4] = fmaf(m, bf_lo(v.z), acc[4]);
            acc[5] = fmaf(m, bf_hi(v.z), acc[5]);
            acc[6] = fmaf(m, bf_lo(v.w), acc[6]);
            acc[7] = fmaf(m, bf_hi(v.w), acc[7]);
        };
        if (mx > 0) {
            int idx[8];
#pragma unroll
            for (int i = 0; i < 8; i++) idx[i] = __shfl(wvC, (hl << 5) + g + 4 * i, 64);
            uint4 rows[8];
#pragma unroll
            for (int i = 0; i < 8; i++) rows[i] = hb4[(size_t)idx[i] * 8 + q];
#pragma unroll
            for (int i = 0; i < 8; i++) procm(rows[i], (g + 4 * i < deg) ? 1.f : 0.f);
            if (mx > 32) {
                int idx2[8];
#pragma unroll
                for (int i = 0; i < 8; i++) idx2[i] = __shfl(wv2C, (hl << 5) + g + 4 * i, 64);
                uint4 rows2[8];
#pragma unroll
                for (int i = 0; i < 8; i++) rows2[i] = hb4[(size_t)idx2[i] * 8 + q];
#pragma unroll
                for (int i = 0; i < 8; i++) procm(rows2[i], (32 + g + 4 * i < deg) ? 1.f : 0.f);
                for (int e = 64 + g; e < deg; e += 4)
                    procm(hb4[(size_t)col[stC + e] * 8 + q], 1.f);
            }
        }
#pragma unroll
        for (int o = 8; o < 32; o <<= 1) {
#pragma unroll
            for (int k = 0; k < 8; k++) acc[k] += __shfl_xor(acc[k], o, 64);
        }
        int node = base + 2 * r + hl;
        bool valid = node < N_NODES;
        int nodeC = valid ? node : 0;
        float vm = valid ? ep : 0.f;
        uint4 v = hb4[(size_t)nodeC * 8 + q];
        acc[0] = fmaf(vm, bf_lo(v.x), acc[0]);
        acc[1] = fmaf(vm, bf_hi(v.x), acc[1]);
        acc[2] = fmaf(vm, bf_lo(v.y), acc[2]);
        acc[3] = fmaf(vm, bf_hi(v.y), acc[3]);
        acc[4] = fmaf(vm, bf_lo(v.z), acc[4]);
        acc[5] = fmaf(vm, bf_hi(v.z), acc[5]);
        acc[6] = fmaf(vm, bf_lo(v.w), acc[6]);
        acc[7] = fmaf(vm, bf_hi(v.w), acc[7]);
        if (!valid) {
#pragma unroll
            for (int k = 0; k < 8; k++) acc[k] = 0.f;
        }
        if (g == 0) {
            int nl = 2 * r + hl;
            *(uint2*)&buf[w][nl][q * 8 + 0] = uint2{packh2(acc[0], acc[1]), packh2(acc[2], acc[3])};
            *(uint2*)&buf[w][nl][q * 8 + 4] = uint2{packh2(acc[4], acc[5]), packh2(acc[6], acc[7])};
        }
        stC = stN; dgC = dgN; mxC = mxN; wvC = wvN; wv2C = wv2N;
    }
    // ---- f16 MFMA MLP (wave-synchronous LDS; no barrier; buf aliased) ----
    int mr = lane & 15, kq = lane >> 4, nc = lane & 15;
    h8v A0 = loadHh(&buf[w][mr][kq * 8]);
    h8v A1 = loadHh(&buf[w][mr][32 + kq * 8]);
#pragma unroll
    for (int nt = 0; nt < 4; nt++) {
        float bb = b1[nt * 16 + nc];
        f4v c = {bb, bb, bb, bb};
        c = mfma16(A0, loadH(W1t + (nt * 16 + nc) * 64 + kq * 8), c);
        c = mfma16(A1, loadH(W1t + (nt * 16 + nc) * 64 + 32 + kq * 8), c);
#pragma unroll
        for (int r2 = 0; r2 < 4; r2++)
            buf[w][kq * 4 + r2][nt * 16 + nc] = (half_t)fmaxf(c[r2], 0.f);
    }
    h8v P0 = loadHh(&buf[w][mr][kq * 8]);
    h8v P1 = loadHh(&buf[w][mr][32 + kq * 8]);
    float sA[4], sB[4];
#pragma unroll
    for (int nt = 0; nt < 4; nt++) { sA[nt] = 0.f; sB[nt] = 0.f; }
#pragma unroll
    for (int nt = 0; nt < 4; nt++) {
        float bb = b2[nt * 16 + nc];
        f4v c = {bb, bb, bb, bb};
        c = mfma16(P0, loadH(W2t + (nt * 16 + nc) * 64 + kq * 8), c);
        c = mfma16(P1, loadH(W2t + (nt * 16 + nc) * 64 + 32 + kq * 8), c);
#pragma unroll
        for (int r2 = 0; r2 < 4; r2++) {
            int node = base + kq * 4 + r2;
            float vv = fmaxf(c[r2], 0.f);
            if (node < N_NODES) {
                sA[nt] += vv;
                sB[nt] = fmaf(vv, vv, sB[nt]);
                hraw[(size_t)node * 64 + nt * 16 + nc] = f2h(vv);
            }
        }
    }
#pragma unroll
    for (int o = 16; o < 64; o <<= 1) {
#pragma unroll
        for (int nt = 0; nt < 4; nt++) {
            sA[nt] += __shfl_xor(sA[nt], o, 64);
            sB[nt] += __shfl_xor(sB[nt], o, 64);
        }
    }
    if (kq == 0) {
        float* pp = part_out + (blockIdx.x & (NSLICE - 1)) * 128;
#pragma unroll
        for (int nt = 0; nt < 4; nt++) {
            atomicAdd(&pp[nt * 16 + nc], sA[nt]);
            atomicAdd(&pp[64 + nt * 16 + nc], sB[nt]);
        }
    }
}

// ---------------------------------------------------------------------------
// Final: fold BN2 partials; out[i] = bf + sum_j relu(h*sc+sh) * Wf[j]
__global__ __launch_bounds__(256) void k_out(const ushort* __restrict__ hraw,
                                             const float* __restrict__ part,
                                             const float* __restrict__ gamma,
                                             const float* __restrict__ beta,
                                             const float* __restrict__ Wf,
                                             const float* __restrict__ bfp,
                                             float* __restrict__ out, int n,
                                             float invn) {
    __shared__ float st[128];
    __shared__ float sc[64], sh[64];
    int t = threadIdx.x;
    if (t < 128) {
        float S = 0.f;
#pragma unroll 8
        for (int s = 0; s < NSLICE; s++) S += part[s * 128 + t];
        st[t] = S;
    }
    __syncthreads();
    if (t < 64) {
        float mu = st[t] * invn;
        float var = fmaxf(st[64 + t] * invn - mu * mu, 0.f);
        float s = gamma[t] * rsqrtf(var + BN_EPS);
        sc[t] = s;
        sh[t] = beta[t] - mu * s;
    }
    __syncthreads();
    int i = blockIdx.x * blockDim.x + threadIdx.x;
    if (i >= n) return;
    float acc = *bfp;
    const uint4* h4 = (const uint4*)(hraw + (size_t)i * 64);
#pragma unroll
    for (int qq = 0; qq < 4; qq++) {
        uint4 v = h4[qq];
        int j = qq * 16;
        float f[8] = {h_lo(v.x), h_hi(v.x), h_lo(v.y), h_hi(v.y),
                      h_lo(v.z), h_hi(v.z), h_lo(v.w), h_hi(v.w)};
#pragma unroll
        for (int k = 0; k < 8; k++)
            acc = fmaf(fmaxf(fmaf(f[k], sc[j + k], sh[j + k]), 0.f), Wf[j + k], acc);
        // second 8 of this 16-chunk come from next uint4; restructure:
    }
    // NOTE: loop above covers 4 uint4 = 32 halves = features 0..31 only if
    // j stepped by 8. Redo cleanly over 8 uint2-sized chunks:
    acc = *bfp;
    const uint2* h2 = (const uint2*)(hraw + (size_t)i * 64);
#pragma unroll
    for (int qq = 0; qq < 16; qq++) {
        uint2 v = h2[qq];
        int j = qq * 4;
        acc = fmaf(fmaxf(fmaf(h_lo(v.x), sc[j + 0], sh[j + 0]), 0.f), Wf[j + 0], acc);
        acc = fmaf(fmaxf(fmaf(h_hi(v.x), sc[j + 1], sh[j + 1]), 0.f), Wf[j + 1], acc);
        acc = fmaf(fmaxf(fmaf(h_lo(v.y), sc[j + 2], sh[j + 2]), 0.f), Wf[j + 2], acc);
        acc = fmaf(fmaxf(fmaf(h_hi(v.y), sc[j + 3], sh[j + 3]), 0.f), Wf[j + 3], acc);
    }
    out[i] = acc;
}

// ---------------------------------------------------------------------------
extern "C" void kernel_launch(void* const* d_in, const int* in_sizes, int n_in,
                              void* d_out, int out_size, void* d_ws, size_t ws_size,
                              hipStream_t stream) {
    const float* x      = (const float*)d_in[0];
    const int*   lab    = (const int*)d_in[1];
    const int*   edge   = (const int*)d_in[2];  // [2][E]: src then dst
    const float* emb    = (const float*)d_in[3];
    const float* W1_0   = (const float*)d_in[4];
    const float* b1_0   = (const float*)d_in[5];
    const float* W2_0   = (const float*)d_in[6];
    const float* b2_0   = (const float*)d_in[7];
    const float* eps_0  = (const float*)d_in[8];
    const float* gamma_0= (const float*)d_in[9];
    const float* beta_0 = (const float*)d_in[10];
    const float* W1_s   = (const float*)d_in[11];
    const float* b1_s   = (const float*)d_in[12];
    const float* W2_s   = (const float*)d_in[13];
    const float* b2_s   = (const float*)d_in[14];
    const float* eps_s  = (const float*)d_in[15];
    const float* gamma_s= (const float*)d_in[16];
    const float* beta_s = (const float*)d_in[17];
    const float* Wf     = (const float*)d_in[18];
    const float* bf     = (const float*)d_in[19];

    const int N = N_NODES, E = N_EDGES;
    const int* srcp = edge;
    const int* dstp = edge + E;

    char* p = (char*)d_ws;
    auto alloc = [&](size_t bytes) {
        void* r = (void*)p;
        p += (bytes + 255) & ~(size_t)255;
        return r;
    };
    int* bucket  = (int*)alloc((size_t)NBLK * BCAP * 4);      // 14.0 MB
    int* col2    = (int*)alloc((size_t)NBLK * BCAP * 4);      // 14.0 MB
    int* gcur    = (int*)alloc((size_t)NBLK * CUR_PAD * 4);   // 50 KB
    int* nodeoff = (int*)alloc((size_t)(N + 64) * 8);         // padded for OOB reads
    ushort* hraw = (ushort*)alloc((size_t)N * 64 * 2);        // 12.8 MB (f16)
    ushort* act  = (ushort*)alloc((size_t)N * 64 * 2);        // 12.8 MB (bf16)
    float* h0    = (float*)alloc((size_t)N * 16 * 4);         //  6.4 MB
    float* parts = (float*)alloc(3 * NSLICE * 128 * 4);       // 48 KB
    ushort* W0t  = (ushort*)alloc(64 * 32 * 2);
    ushort* W20t = (ushort*)alloc(4096 * 2);
    ushort* Wst  = (ushort*)alloc(2 * 8192 * 2);

    hipMemsetAsync(gcur, 0, (size_t)NBLK * CUR_PAD * 4, stream);
    hipMemsetAsync(parts, 0, 3 * NSLICE * 128 * 4, stream);

    const int TB = 256;
    const int gN = (N + TB - 1) / TB;
    const int gM = (N + 63) / 64;  // 1563 blocks, 64 nodes each
    const int gA = N * 64 / 1024;
    const float invn = 1.0f / (float)N;

    k_h0<<<gN, TB, 0, stream>>>(x, lab, emb, h0, N);
    k_wcvt<<<1, TB, 0, stream>>>(W1_0, W2_0, W1_s, W2_s, W0t, W20t, Wst);
    k_fill<<<NW, TB, 0, stream>>>(srcp, dstp, gcur, bucket);
    k_sort<<<NBLK, TB, 0, stream>>>(gcur, bucket, col2, (int2*)nodeoff, N);

    // ---- Layer 0 ----
    k_layer0M<<<gM, TB, 0, stream>>>(h0, (const int2*)nodeoff, col2, eps_0, W0t,
                                     b1_0, W20t, b2_0, hraw,
                                     parts + 0 * NSLICE * 128);
    k_act<<<gA, TB, 0, stream>>>(hraw, parts + 0 * NSLICE * 128, gamma_0, beta_0,
                                 act, invn);

    // ---- Layer 1 ----
    k_layerM<<<gM, TB, 0, stream>>>((const uint*)act, (const int2*)nodeoff, col2,
                                    eps_s + 0, Wst + 0 * 8192, b1_s + 0 * 64,
                                    Wst + 0 * 8192 + 4096, b2_s + 0 * 64,
                                    hraw, parts + 1 * NSLICE * 128);
    k_act<<<gA, TB, 0, stream>>>(hraw, parts + 1 * NSLICE * 128, gamma_s + 0 * 64,
                                 beta_s + 0 * 64, act, invn);

    // ---- Layer 2 ----
    k_layerM<<<gM, TB, 0, stream>>>((const uint*)act, (const int2*)nodeoff, col2,
                                    eps_s + 1, Wst + 1 * 8192, b1_s + 1 * 64,
                                    Wst + 1 * 8192 + 4096, b2_s + 1 * 64,
                                    hraw, parts + 2 * NSLICE * 128);

    // ---- Output (BN2 folded from partials) ----
    k_out<<<gN, TB, 0, stream>>>(hraw, parts + 2 * NSLICE * 128,
                                 gamma_s + 1 * 64, beta_s + 1 * 64, Wf, bf,
                                 (float*)d_out, N, invn);
}

// Round 18
// 394.847 us; speedup vs baseline: 1.0997x; 1.0997x over previous
//
#include <hip/hip_runtime.h>

#define N_NODES 100000
#define N_EDGES 3200000
#define BN_EPS 1e-5f

#define BLK_NODES 128            // nodes per bin block
#define NBLK 782                 // ceil(100000/128)
#define CHUNK 16384              // edges per fill workgroup (196 wgs; long runs
                                 // -> L2 write-combining; 4096 regressed 2x)
#define NW ((N_EDGES + CHUNK - 1) / CHUNK)  // 196
#define BCAP 4480                // words per bin (mean 4094, ~6 sigma)
#define CUR_PAD 16               // ints per cursor -> 64B
#define NSLICE 32                // stat partial slices

typedef unsigned int uint;
typedef unsigned short ushort;
typedef _Float16 half_t;
typedef __attribute__((ext_vector_type(8))) _Float16 h8v;  // 8 f16 (4 VGPRs)
typedef __attribute__((ext_vector_type(4))) float f4v;     // MFMA C/D

__device__ inline float bf_lo(uint u) { return __uint_as_float(u << 16); }
__device__ inline float bf_hi(uint u) { return __uint_as_float(u & 0xffff0000u); }
__device__ inline float h_lo(uint u) {
    union { ushort s; half_t h; } r; r.s = (ushort)(u & 0xffffu); return (float)r.h;
}
__device__ inline float h_hi(uint u) {
    union { ushort s; half_t h; } r; r.s = (ushort)(u >> 16); return (float)r.h;
}
__device__ inline ushort f2bf(float a) {
    uint ua = __float_as_uint(a); ua += 0x7fffu + ((ua >> 16) & 1u);
    return (ushort)(ua >> 16);
}
__device__ inline ushort f2h(float a) {
    union { half_t h; ushort u; } r;
    r.h = (half_t)a;
    return r.u;
}
__device__ inline uint packh2(float a, float b) {
    return (uint)f2h(a) | ((uint)f2h(b) << 16);
}
__device__ inline h8v loadH(const ushort* p) {
    union { uint4 q; h8v f; } r;
    r.q = *(const uint4*)p;
    return r.f;
}
__device__ inline h8v loadHh(const half_t* p) {
    union { uint4 q; h8v f; } r;
    r.q = *(const uint4*)p;
    return r.f;
}
__device__ inline f4v mfma16(h8v a, h8v b, f4v c) {
    return __builtin_amdgcn_mfma_f32_16x16x32_f16(a, b, c, 0, 0, 0);
}

// ---------------------------------------------------------------------------
// Build h0 [N,16]: [x0, x1, emb[label][0..7], 0 x6]
__global__ __launch_bounds__(256) void k_h0(const float* __restrict__ x,
                                            const int* __restrict__ lab,
                                            const float* __restrict__ emb,
                                            float* __restrict__ h0, int n) {
    int i = blockIdx.x * blockDim.x + threadIdx.x;
    if (i >= n) return;
    float v[16];
    v[0] = x[2 * i];
    v[1] = x[2 * i + 1];
    int L = lab[i];
#pragma unroll
    for (int k = 0; k < 8; k++) v[2 + k] = emb[L * 8 + k];
#pragma unroll
    for (int k = 10; k < 16; k++) v[k] = 0.f;
    float4* o = (float4*)(h0 + (size_t)i * 16);
#pragma unroll
    for (int q = 0; q < 4; q++) {
        float4 t;
        t.x = v[4 * q]; t.y = v[4 * q + 1]; t.z = v[4 * q + 2]; t.w = v[4 * q + 3];
        o[q] = t;
    }
}

// ---------------------------------------------------------------------------
// Weight convert/transpose to f16: Wt[n][k] so B-frag reads are contiguous.
__global__ __launch_bounds__(256) void k_wcvt(const float* __restrict__ W1_0,
                                              const float* __restrict__ W2_0,
                                              const float* __restrict__ W1_s,
                                              const float* __restrict__ W2_s,
                                              ushort* __restrict__ W0t,
                                              ushort* __restrict__ W20t,
                                              ushort* __restrict__ Wst) {
    int t = threadIdx.x;
    for (int i = t; i < 64 * 32; i += 256) {       // W0t [64][32], K padded
        int n = i >> 5, k = i & 31;
        W0t[i] = (k < 10) ? f2h(W1_0[k * 64 + n]) : (ushort)0;
    }
    for (int i = t; i < 4096; i += 256) {          // W20t [64][64]
        int n = i >> 6, k = i & 63;
        W20t[i] = f2h(W2_0[k * 64 + n]);
    }
    for (int l = 0; l < 2; l++) {
        const float* w1 = W1_s + l * 4096;
        const float* w2 = W2_s + l * 4096;
        for (int i = t; i < 4096; i += 256) {
            int n = i >> 6, k = i & 63;
            Wst[l * 8192 + i] = f2h(w1[k * 64 + n]);
            Wst[l * 8192 + 4096 + i] = f2h(w2[k * 64 + n]);
        }
    }
}

// ---------------------------------------------------------------------------
// LDS-binned fill: count chunk into 782 bins, reserve contiguous runs
// (1 atomic per wg-bin), stream words into runs. CHUNK=16384: ~21-word runs
// assemble full lines in L2 (write amp ~2x); smaller chunks regress (r17).
__global__ __launch_bounds__(256) void k_fill(const int* __restrict__ src,
                                              const int* __restrict__ dst,
                                              int* __restrict__ gcur,
                                              int* __restrict__ bucket) {
    __shared__ int cnt[NBLK];
    __shared__ int off[NBLK];
    int t = threadIdx.x;
    for (int b = t; b < NBLK; b += 256) cnt[b] = 0;
    __syncthreads();
    int my0 = blockIdx.x * CHUNK + t * 64;
    for (int k = 0; k < 64; k += 4) {
        int e = my0 + k;
        if (e + 3 < N_EDGES) {
            int4 d4 = *(const int4*)(dst + e);
            atomicAdd(&cnt[d4.x >> 7], 1);
            atomicAdd(&cnt[d4.y >> 7], 1);
            atomicAdd(&cnt[d4.z >> 7], 1);
            atomicAdd(&cnt[d4.w >> 7], 1);
        } else {
#pragma unroll
            for (int kk = 0; kk < 4; kk++) {
                int ee = e + kk;
                if (ee < N_EDGES) atomicAdd(&cnt[dst[ee] >> 7], 1);
            }
        }
    }
    __syncthreads();
    for (int b = t; b < NBLK; b += 256) {
        int c = cnt[b];
        off[b] = (c > 0) ? atomicAdd(&gcur[b * CUR_PAD], c) : 0;
    }
    __syncthreads();
    for (int k = 0; k < 64; k += 4) {
        int e = my0 + k;
        if (e + 3 < N_EDGES) {
            int4 d4 = *(const int4*)(dst + e);
            int4 s4 = *(const int4*)(src + e);
            int dd[4] = {d4.x, d4.y, d4.z, d4.w};
            int ss[4] = {s4.x, s4.y, s4.z, s4.w};
#pragma unroll
            for (int kk = 0; kk < 4; kk++) {
                int b = dd[kk] >> 7;
                int p = atomicAdd(&off[b], 1);
                if (p < BCAP)
                    bucket[(size_t)b * BCAP + p] = ((dd[kk] & 127) << 17) | ss[kk];
            }
        } else {
#pragma unroll
            for (int kk = 0; kk < 4; kk++) {
                int ee = e + kk;
                if (ee < N_EDGES) {
                    int d = dst[ee], s = src[ee];
                    int b = d >> 7;
                    int p = atomicAdd(&off[b], 1);
                    if (p < BCAP)
                        bucket[(size_t)b * BCAP + p] = ((d & 127) << 17) | s;
                }
            }
        }
    }
}

// ---------------------------------------------------------------------------
// Per-block counting sort -> per-node-contiguous col2 + nodeoff = (start,deg)
__global__ __launch_bounds__(256) void k_sort(const int* __restrict__ gcur,
                                              const int* __restrict__ bucket,
                                              int* __restrict__ col2,
                                              int2* __restrict__ nodeoff, int n) {
    __shared__ int cnt[BLK_NODES];
    __shared__ int scn[BLK_NODES];
    __shared__ int cur[BLK_NODES];
    int t = threadIdx.x;
    int blk = blockIdx.x;
    if (t < BLK_NODES) cnt[t] = 0;
    __syncthreads();
    int cc = min(gcur[blk * CUR_PAD], BCAP);
    const int* bb = bucket + (size_t)blk * BCAP;
    for (int i = t; i < cc; i += 256) atomicAdd(&cnt[bb[i] >> 17], 1);
    __syncthreads();
    if (t < BLK_NODES) scn[t] = cnt[t];
    __syncthreads();
#pragma unroll
    for (int off = 1; off < BLK_NODES; off <<= 1) {
        int v = (t >= off && t < BLK_NODES) ? scn[t - off] : 0;
        __syncthreads();
        if (t < BLK_NODES) scn[t] += v;
        __syncthreads();
    }
    if (t < BLK_NODES) {
        int start = scn[t] - cnt[t];
        cur[t] = start;
        int node = blk * BLK_NODES + t;
        if (node < n) nodeoff[node] = int2{blk * BCAP + start, cnt[t]};
    }
    __syncthreads();
    int* out = col2 + (size_t)blk * BCAP;
    for (int i = t; i < cc; i += 256) {
        int w = bb[i];
        int p = atomicAdd(&cur[w >> 17], 1);
        out[p] = w & 0x1FFFF;
    }
}

// ---------------------------------------------------------------------------
// Layer 0: block = 4 waves = 64 nodes. Gather16 (2 nodes/wave x 8 rounds,
// depth-2 col pipeline) into wave-private f16 LDS, then f16 MFMA MLP + stats.
__global__ __launch_bounds__(256, 4) void k_layer0M(const float* __restrict__ h0,
                                                    const int2* __restrict__ nodeoff,
                                                    const int* __restrict__ col,
                                                    const float* __restrict__ epsp,
                                                    const ushort* __restrict__ W0t,
                                                    const float* __restrict__ b1,
                                                    const ushort* __restrict__ W20t,
                                                    const float* __restrict__ b2,
                                                    ushort* __restrict__ hraw,
                                                    float* __restrict__ part_out) {
    __shared__ half_t buf[4][16][72];   // comb (cols 0..31) then h1 (cols 0..63)
    int t = threadIdx.x, w = t >> 6, lane = t & 63;
    int base = blockIdx.x * 64 + w * 16;
    float ep = 1.f + *epsp;
    int hl = lane >> 5, l5 = lane & 31;
    int q = l5 & 3, g = l5 >> 2;  // 8 groups x 4 lanes per half
    const float4* h4 = (const float4*)h0;

    int nj = base + (lane & 15);
    int2 no2 = nodeoff[nj];  // padded past N
    int myStart = no2.x;
    int myDeg = (nj < N_NODES) ? no2.y : 0;

    int stC, dgC, mxC, wvC, wv2C;
    {
        stC = __shfl(myStart, hl, 64);
        dgC = __shfl(myDeg, hl, 64);
        int dA = __shfl(myDeg, 0, 64), dB = __shfl(myDeg, 1, 64);
        mxC = max(dA, dB);
        wvC = (dgC > 0) ? col[stC + min(l5, dgC - 1)] : 0;
        wv2C = (mxC > 32) ? ((dgC > 32) ? col[stC + min(32 + l5, dgC - 1)] : wvC) : 0;
    }

    for (int r = 0; r < 8; r++) {
        int stN = 0, dgN = 0, mxN = 0, wvN = 0, wv2N = 0;
        if (r < 7) {
            stN = __shfl(myStart, 2 * (r + 1) + hl, 64);
            dgN = __shfl(myDeg, 2 * (r + 1) + hl, 64);
            int dA = __shfl(myDeg, 2 * (r + 1), 64);
            int dB = __shfl(myDeg, 2 * (r + 1) + 1, 64);
            mxN = max(dA, dB);
            wvN = (dgN > 0) ? col[stN + min(l5, dgN - 1)] : 0;
            wv2N = (mxN > 32) ? ((dgN > 32) ? col[stN + min(32 + l5, dgN - 1)] : wvN) : 0;
        }
        int deg = dgC, mx = mxC;
        float ac[4] = {0.f, 0.f, 0.f, 0.f};
        if (mx > 0) {
            int idx[4];
#pragma unroll
            for (int i = 0; i < 4; i++) idx[i] = __shfl(wvC, (hl << 5) + g + 8 * i, 64);
            float4 rows[4];
#pragma unroll
            for (int i = 0; i < 4; i++) rows[i] = h4[(size_t)idx[i] * 4 + q];
#pragma unroll
            for (int i = 0; i < 4; i++) {
                float m = (g + 8 * i < deg) ? 1.f : 0.f;
                ac[0] = fmaf(m, rows[i].x, ac[0]);
                ac[1] = fmaf(m, rows[i].y, ac[1]);
                ac[2] = fmaf(m, rows[i].z, ac[2]);
                ac[3] = fmaf(m, rows[i].w, ac[3]);
            }
            if (mx > 32) {
                int idx2[4];
#pragma unroll
                for (int i = 0; i < 4; i++) idx2[i] = __shfl(wv2C, (hl << 5) + g + 8 * i, 64);
                float4 rows2[4];
#pragma unroll
                for (int i = 0; i < 4; i++) rows2[i] = h4[(size_t)idx2[i] * 4 + q];
#pragma unroll
                for (int i = 0; i < 4; i++) {
                    float m = (32 + g + 8 * i < deg) ? 1.f : 0.f;
                    ac[0] = fmaf(m, rows2[i].x, ac[0]);
                    ac[1] = fmaf(m, rows2[i].y, ac[1]);
                    ac[2] = fmaf(m, rows2[i].z, ac[2]);
                    ac[3] = fmaf(m, rows2[i].w, ac[3]);
                }
                for (int e = 64 + g; e < deg; e += 8) {
                    float4 v = h4[(size_t)col[stC + e] * 4 + q];
                    ac[0] += v.x; ac[1] += v.y; ac[2] += v.z; ac[3] += v.w;
                }
            }
        }
#pragma unroll
        for (int o = 4; o < 32; o <<= 1) {
#pragma unroll
            for (int k = 0; k < 4; k++) ac[k] += __shfl_xor(ac[k], o, 64);
        }
        int node = base + 2 * r + hl;
        bool valid = node < N_NODES;
        int nodeC = valid ? node : 0;
        float vm = valid ? ep : 0.f;
        float4 xi = h4[(size_t)nodeC * 4 + q];
        ac[0] = fmaf(vm, xi.x, ac[0]);
        ac[1] = fmaf(vm, xi.y, ac[1]);
        ac[2] = fmaf(vm, xi.z, ac[2]);
        ac[3] = fmaf(vm, xi.w, ac[3]);
        if (!valid) { ac[0] = ac[1] = ac[2] = ac[3] = 0.f; }
        if (g == 0) {
            int nl = 2 * r + hl;
            *(uint2*)&buf[w][nl][q * 4] = uint2{packh2(ac[0], ac[1]), packh2(ac[2], ac[3])};
            *(uint2*)&buf[w][nl][16 + q * 4] = uint2{0u, 0u};
        }
        stC = stN; dgC = dgN; mxC = mxN; wvC = wvN; wv2C = wv2N;
    }
    // ---- f16 MFMA MLP (wave-synchronous LDS; no barrier; buf aliased) ----
    int mr = lane & 15, kq = lane >> 4, nc = lane & 15;
    h8v A0 = loadHh(&buf[w][mr][kq * 8]);
#pragma unroll
    for (int nt = 0; nt < 4; nt++) {
        float bb = b1[nt * 16 + nc];
        f4v c = {bb, bb, bb, bb};
        c = mfma16(A0, loadH(W0t + (nt * 16 + nc) * 32 + kq * 8), c);
#pragma unroll
        for (int r2 = 0; r2 < 4; r2++)
            buf[w][kq * 4 + r2][nt * 16 + nc] = (half_t)fmaxf(c[r2], 0.f);
    }
    h8v P0 = loadHh(&buf[w][mr][kq * 8]);
    h8v P1 = loadHh(&buf[w][mr][32 + kq * 8]);
    float sA[4], sB[4];
#pragma unroll
    for (int nt = 0; nt < 4; nt++) { sA[nt] = 0.f; sB[nt] = 0.f; }
#pragma unroll
    for (int nt = 0; nt < 4; nt++) {
        float bb = b2[nt * 16 + nc];
        f4v c = {bb, bb, bb, bb};
        c = mfma16(P0, loadH(W20t + (nt * 16 + nc) * 64 + kq * 8), c);
        c = mfma16(P1, loadH(W20t + (nt * 16 + nc) * 64 + 32 + kq * 8), c);
#pragma unroll
        for (int r2 = 0; r2 < 4; r2++) {
            int node = base + kq * 4 + r2;
            float vv = fmaxf(c[r2], 0.f);
            if (node < N_NODES) {
                sA[nt] += vv;
                sB[nt] = fmaf(vv, vv, sB[nt]);
                hraw[(size_t)node * 64 + nt * 16 + nc] = f2h(vv);
            }
        }
    }
#pragma unroll
    for (int o = 16; o < 64; o <<= 1) {
#pragma unroll
        for (int nt = 0; nt < 4; nt++) {
            sA[nt] += __shfl_xor(sA[nt], o, 64);
            sB[nt] += __shfl_xor(sB[nt], o, 64);
        }
    }
    if (kq == 0) {
        float* pp = part_out + (blockIdx.x & (NSLICE - 1)) * 128;
#pragma unroll
        for (int nt = 0; nt < 4; nt++) {
            atomicAdd(&pp[nt * 16 + nc], sA[nt]);
            atomicAdd(&pp[64 + nt * 16 + nc], sB[nt]);
        }
    }
}

// ---------------------------------------------------------------------------
// Activation pass: act = bf16(relu(h*sc+sh)), h stored f16, BN from partials.
__global__ __launch_bounds__(256) void k_act(const ushort* __restrict__ hraw,
                                             const float* __restrict__ part,
                                             const float* __restrict__ gamma,
                                             const float* __restrict__ beta,
                                             ushort* __restrict__ act, float invn) {
    __shared__ float st[128];
    __shared__ float sc[64], sh[64];
    int t = threadIdx.x;
    if (t < 128) {
        float S = 0.f;
#pragma unroll 8
        for (int s = 0; s < NSLICE; s++) S += part[s * 128 + t];
        st[t] = S;
    }
    __syncthreads();
    if (t < 64) {
        float mu = st[t] * invn;
        float var = fmaxf(st[64 + t] * invn - mu * mu, 0.f);
        float s = gamma[t] * rsqrtf(var + BN_EPS);
        sc[t] = s;
        sh[t] = beta[t] - mu * s;
    }
    __syncthreads();
    int base = (blockIdx.x * 256 + t) * 4;
    int f0 = base & 63;
    uint2 hv = *(const uint2*)(hraw + base);
    float a0 = fmaxf(fmaf(h_lo(hv.x), sc[f0 + 0], sh[f0 + 0]), 0.f);
    float a1 = fmaxf(fmaf(h_hi(hv.x), sc[f0 + 1], sh[f0 + 1]), 0.f);
    float a2 = fmaxf(fmaf(h_lo(hv.y), sc[f0 + 2], sh[f0 + 2]), 0.f);
    float a3 = fmaxf(fmaf(h_hi(hv.y), sc[f0 + 3], sh[f0 + 3]), 0.f);
    uint2 o;
    o.x = (uint)f2bf(a0) | ((uint)f2bf(a1) << 16);
    o.y = (uint)f2bf(a2) | ((uint)f2bf(a3) << 16);
    *(uint2*)(act + base) = o;
}

// ---------------------------------------------------------------------------
// Layers 1/2: block = 4 waves = 64 nodes. Gather64 over pre-activated bf16
// (2 nodes/wave x 8 rounds, depth-2 col pipeline) into wave-private f16 LDS,
// then f16 MFMA MLP + stats + f16 store.
__global__ __launch_bounds__(256, 4) void k_layerM(const uint* __restrict__ actin,
                                                   const int2* __restrict__ nodeoff,
                                                   const int* __restrict__ col,
                                                   const float* __restrict__ epsp,
                                                   const ushort* __restrict__ W1t,
                                                   const float* __restrict__ b1,
                                                   const ushort* __restrict__ W2t,
                                                   const float* __restrict__ b2,
                                                   ushort* __restrict__ hraw,
                                                   float* __restrict__ part_out) {
    __shared__ half_t buf[4][16][72];   // comb then h1 (aliased, wave-private)
    int t = threadIdx.x, w = t >> 6, lane = t & 63;
    int base = blockIdx.x * 64 + w * 16;
    float ep = 1.f + *epsp;
    int hl = lane >> 5, l5 = lane & 31;
    int q = l5 & 7, g = l5 >> 3;  // 4 groups x 8 lanes per half
    const uint4* hb4 = (const uint4*)actin;

    int nj = base + (lane & 15);
    int2 no2 = nodeoff[nj];
    int myStart = no2.x;
    int myDeg = (nj < N_NODES) ? no2.y : 0;

    int stC, dgC, mxC, wvC, wv2C;
    {
        stC = __shfl(myStart, hl, 64);
        dgC = __shfl(myDeg, hl, 64);
        int dA = __shfl(myDeg, 0, 64), dB = __shfl(myDeg, 1, 64);
        mxC = max(dA, dB);
        wvC = (dgC > 0) ? col[stC + min(l5, dgC - 1)] : 0;
        wv2C = (mxC > 32) ? ((dgC > 32) ? col[stC + min(32 + l5, dgC - 1)] : wvC) : 0;
    }

    for (int r = 0; r < 8; r++) {
        int stN = 0, dgN = 0, mxN = 0, wvN = 0, wv2N = 0;
        if (r < 7) {
            stN = __shfl(myStart, 2 * (r + 1) + hl, 64);
            dgN = __shfl(myDeg, 2 * (r + 1) + hl, 64);
            int dA = __shfl(myDeg, 2 * (r + 1), 64);
            int dB = __shfl(myDeg, 2 * (r + 1) + 1, 64);
            mxN = max(dA, dB);
            wvN = (dgN > 0) ? col[stN + min(l5, dgN - 1)] : 0;
            wv2N = (mxN > 32) ? ((dgN > 32) ? col[stN + min(32 + l5, dgN - 1)] : wvN) : 0;
        }
        int deg = dgC, mx = mxC;
        float acc[8];
#pragma unroll
        for (int k = 0; k < 8; k++) acc[k] = 0.f;
        auto procm = [&](uint4 v, float m) {
            acc[0] = fmaf(m, bf_lo(v.x), acc[0]);
            acc[1] = fmaf(m, bf_hi(v.x), acc[1]);
            acc[2] = fmaf(m, bf_lo(v.y), acc[2]);
            acc[3] = fmaf(m, bf_hi(v.y), acc[3]);
            acc[4] = fmaf(m, bf_lo(v.z), acc[4]);
            acc[5] = fmaf(m, bf_hi(v.z), acc[5]);
            acc[6] = fmaf(m, bf_lo(v.w), acc[6]);
            acc[7] = fmaf(m, bf_hi(v.w), acc[7]);
        };
        if (mx > 0) {
            int idx[8];
#pragma unroll
            for (int i = 0; i < 8; i++) idx[i] = __shfl(wvC, (hl << 5) + g + 4 * i, 64);
            uint4 rows[8];
#pragma unroll
            for (int i = 0; i < 8; i++) rows[i] = hb4[(size_t)idx[i] * 8 + q];
#pragma unroll
            for (int i = 0; i < 8; i++) procm(rows[i], (g + 4 * i < deg) ? 1.f : 0.f);
            if (mx > 32) {
                int idx2[8];
#pragma unroll
                for (int i = 0; i < 8; i++) idx2[i] = __shfl(wv2C, (hl << 5) + g + 4 * i, 64);
                uint4 rows2[8];
#pragma unroll
                for (int i = 0; i < 8; i++) rows2[i] = hb4[(size_t)idx2[i] * 8 + q];
#pragma unroll
                for (int i = 0; i < 8; i++) procm(rows2[i], (32 + g + 4 * i < deg) ? 1.f : 0.f);
                for (int e = 64 + g; e < deg; e += 4)
                    procm(hb4[(size_t)col[stC + e] * 8 + q], 1.f);
            }
        }
#pragma unroll
        for (int o = 8; o < 32; o <<= 1) {
#pragma unroll
            for (int k = 0; k < 8; k++) acc[k] += __shfl_xor(acc[k], o, 64);
        }
        int node = base + 2 * r + hl;
        bool valid = node < N_NODES;
        int nodeC = valid ? node : 0;
        float vm = valid ? ep : 0.f;
        uint4 v = hb4[(size_t)nodeC * 8 + q];
        acc[0] = fmaf(vm, bf_lo(v.x), acc[0]);
        acc[1] = fmaf(vm, bf_hi(v.x), acc[1]);
        acc[2] = fmaf(vm, bf_lo(v.y), acc[2]);
        acc[3] = fmaf(vm, bf_hi(v.y), acc[3]);
        acc[4] = fmaf(vm, bf_lo(v.z), acc[4]);
        acc[5] = fmaf(vm, bf_hi(v.z), acc[5]);
        acc[6] = fmaf(vm, bf_lo(v.w), acc[6]);
        acc[7] = fmaf(vm, bf_hi(v.w), acc[7]);
        if (!valid) {
#pragma unroll
            for (int k = 0; k < 8; k++) acc[k] = 0.f;
        }
        if (g == 0) {
            int nl = 2 * r + hl;
            *(uint2*)&buf[w][nl][q * 8 + 0] = uint2{packh2(acc[0], acc[1]), packh2(acc[2], acc[3])};
            *(uint2*)&buf[w][nl][q * 8 + 4] = uint2{packh2(acc[4], acc[5]), packh2(acc[6], acc[7])};
        }
        stC = stN; dgC = dgN; mxC = mxN; wvC = wvN; wv2C = wv2N;
    }
    // ---- f16 MFMA MLP (wave-synchronous LDS; no barrier; buf aliased) ----
    int mr = lane & 15, kq = lane >> 4, nc = lane & 15;
    h8v A0 = loadHh(&buf[w][mr][kq * 8]);
    h8v A1 = loadHh(&buf[w][mr][32 + kq * 8]);
#pragma unroll
    for (int nt = 0; nt < 4; nt++) {
        float bb = b1[nt * 16 + nc];
        f4v c = {bb, bb, bb, bb};
        c = mfma16(A0, loadH(W1t + (nt * 16 + nc) * 64 + kq * 8), c);
        c = mfma16(A1, loadH(W1t + (nt * 16 + nc) * 64 + 32 + kq * 8), c);
#pragma unroll
        for (int r2 = 0; r2 < 4; r2++)
            buf[w][kq * 4 + r2][nt * 16 + nc] = (half_t)fmaxf(c[r2], 0.f);
    }
    h8v P0 = loadHh(&buf[w][mr][kq * 8]);
    h8v P1 = loadHh(&buf[w][mr][32 + kq * 8]);
    float sA[4], sB[4];
#pragma unroll
    for (int nt = 0; nt < 4; nt++) { sA[nt] = 0.f; sB[nt] = 0.f; }
#pragma unroll
    for (int nt = 0; nt < 4; nt++) {
        float bb = b2[nt * 16 + nc];
        f4v c = {bb, bb, bb, bb};
        c = mfma16(P0, loadH(W2t + (nt * 16 + nc) * 64 + kq * 8), c);
        c = mfma16(P1, loadH(W2t + (nt * 16 + nc) * 64 + 32 + kq * 8), c);
#pragma unroll
        for (int r2 = 0; r2 < 4; r2++) {
            int node = base + kq * 4 + r2;
            float vv = fmaxf(c[r2], 0.f);
            if (node < N_NODES) {
                sA[nt] += vv;
                sB[nt] = fmaf(vv, vv, sB[nt]);
                hraw[(size_t)node * 64 + nt * 16 + nc] = f2h(vv);
            }
        }
    }
#pragma unroll
    for (int o = 16; o < 64; o <<= 1) {
#pragma unroll
        for (int nt = 0; nt < 4; nt++) {
            sA[nt] += __shfl_xor(sA[nt], o, 64);
            sB[nt] += __shfl_xor(sB[nt], o, 64);
        }
    }
    if (kq == 0) {
        float* pp = part_out + (blockIdx.x & (NSLICE - 1)) * 128;
#pragma unroll
        for (int nt = 0; nt < 4; nt++) {
            atomicAdd(&pp[nt * 16 + nc], sA[nt]);
            atomicAdd(&pp[64 + nt * 16 + nc], sB[nt]);
        }
    }
}

// ---------------------------------------------------------------------------
// Final: fold BN2 partials; out[i] = bf + sum_j relu(h*sc+sh) * Wf[j]
__global__ __launch_bounds__(256) void k_out(const ushort* __restrict__ hraw,
                                             const float* __restrict__ part,
                                             const float* __restrict__ gamma,
                                             const float* __restrict__ beta,
                                             const float* __restrict__ Wf,
                                             const float* __restrict__ bfp,
                                             float* __restrict__ out, int n,
                                             float invn) {
    __shared__ float st[128];
    __shared__ float sc[64], sh[64];
    int t = threadIdx.x;
    if (t < 128) {
        float S = 0.f;
#pragma unroll 8
        for (int s = 0; s < NSLICE; s++) S += part[s * 128 + t];
        st[t] = S;
    }
    __syncthreads();
    if (t < 64) {
        float mu = st[t] * invn;
        float var = fmaxf(st[64 + t] * invn - mu * mu, 0.f);
        float s = gamma[t] * rsqrtf(var + BN_EPS);
        sc[t] = s;
        sh[t] = beta[t] - mu * s;
    }
    __syncthreads();
    int i = blockIdx.x * blockDim.x + threadIdx.x;
    if (i >= n) return;
    float acc = *bfp;
    const uint2* h2 = (const uint2*)(hraw + (size_t)i * 64);
#pragma unroll
    for (int qq = 0; qq < 16; qq++) {
        uint2 v = h2[qq];
        int j = qq * 4;
        acc = fmaf(fmaxf(fmaf(h_lo(v.x), sc[j + 0], sh[j + 0]), 0.f), Wf[j + 0], acc);
        acc = fmaf(fmaxf(fmaf(h_hi(v.x), sc[j + 1], sh[j + 1]), 0.f), Wf[j + 1], acc);
        acc = fmaf(fmaxf(fmaf(h_lo(v.y), sc[j + 2], sh[j + 2]), 0.f), Wf[j + 2], acc);
        acc = fmaf(fmaxf(fmaf(h_hi(v.y), sc[j + 3], sh[j + 3]), 0.f), Wf[j + 3], acc);
    }
    out[i] = acc;
}

// ---------------------------------------------------------------------------
extern "C" void kernel_launch(void* const* d_in, const int* in_sizes, int n_in,
                              void* d_out, int out_size, void* d_ws, size_t ws_size,
                              hipStream_t stream) {
    const float* x      = (const float*)d_in[0];
    const int*   lab    = (const int*)d_in[1];
    const int*   edge   = (const int*)d_in[2];  // [2][E]: src then dst
    const float* emb    = (const float*)d_in[3];
    const float* W1_0   = (const float*)d_in[4];
    const float* b1_0   = (const float*)d_in[5];
    const float* W2_0   = (const float*)d_in[6];
    const float* b2_0   = (const float*)d_in[7];
    const float* eps_0  = (const float*)d_in[8];
    const float* gamma_0= (const float*)d_in[9];
    const float* beta_0 = (const float*)d_in[10];
    const float* W1_s   = (const float*)d_in[11];
    const float* b1_s   = (const float*)d_in[12];
    const float* W2_s   = (const float*)d_in[13];
    const float* b2_s   = (const float*)d_in[14];
    const float* eps_s  = (const float*)d_in[15];
    const float* gamma_s= (const float*)d_in[16];
    const float* beta_s = (const float*)d_in[17];
    const float* Wf     = (const float*)d_in[18];
    const float* bf     = (const float*)d_in[19];

    const int N = N_NODES, E = N_EDGES;
    const int* srcp = edge;
    const int* dstp = edge + E;

    char* p = (char*)d_ws;
    auto alloc = [&](size_t bytes) {
        void* r = (void*)p;
        p += (bytes + 255) & ~(size_t)255;
        return r;
    };
    int* bucket  = (int*)alloc((size_t)NBLK * BCAP * 4);      // 14.0 MB
    int* col2    = (int*)alloc((size_t)NBLK * BCAP * 4);      // 14.0 MB
    int* gcur    = (int*)alloc((size_t)NBLK * CUR_PAD * 4);   // 50 KB
    int* nodeoff = (int*)alloc((size_t)(N + 64) * 8);         // padded for OOB reads
    ushort* hraw = (ushort*)alloc((size_t)N * 64 * 2);        // 12.8 MB (f16)
    ushort* act  = (ushort*)alloc((size_t)N * 64 * 2);        // 12.8 MB (bf16)
    float* h0    = (float*)alloc((size_t)N * 16 * 4);         //  6.4 MB
    float* parts = (float*)alloc(3 * NSLICE * 128 * 4);       // 48 KB
    ushort* W0t  = (ushort*)alloc(64 * 32 * 2);
    ushort* W20t = (ushort*)alloc(4096 * 2);
    ushort* Wst  = (ushort*)alloc(2 * 8192 * 2);

    hipMemsetAsync(gcur, 0, (size_t)NBLK * CUR_PAD * 4, stream);
    hipMemsetAsync(parts, 0, 3 * NSLICE * 128 * 4, stream);

    const int TB = 256;
    const int gN = (N + TB - 1) / TB;
    const int gM = (N + 63) / 64;  // 1563 blocks, 64 nodes each
    const int gA = N * 64 / 1024;
    const float invn = 1.0f / (float)N;

    k_h0<<<gN, TB, 0, stream>>>(x, lab, emb, h0, N);
    k_wcvt<<<1, TB, 0, stream>>>(W1_0, W2_0, W1_s, W2_s, W0t, W20t, Wst);
    k_fill<<<NW, TB, 0, stream>>>(srcp, dstp, gcur, bucket);
    k_sort<<<NBLK, TB, 0, stream>>>(gcur, bucket, col2, (int2*)nodeoff, N);

    // ---- Layer 0 ----
    k_layer0M<<<gM, TB, 0, stream>>>(h0, (const int2*)nodeoff, col2, eps_0, W0t,
                                     b1_0, W20t, b2_0, hraw,
                                     parts + 0 * NSLICE * 128);
    k_act<<<gA, TB, 0, stream>>>(hraw, parts + 0 * NSLICE * 128, gamma_0, beta_0,
                                 act, invn);

    // ---- Layer 1 ----
    k_layerM<<<gM, TB, 0, stream>>>((const uint*)act, (const int2*)nodeoff, col2,
                                    eps_s + 0, Wst + 0 * 8192, b1_s + 0 * 64,
                                    Wst + 0 * 8192 + 4096, b2_s + 0 * 64,
                                    hraw, parts + 1 * NSLICE * 128);
    k_act<<<gA, TB, 0, stream>>>(hraw, parts + 1 * NSLICE * 128, gamma_s + 0 * 64,
                                 beta_s + 0 * 64, act, invn);

    // ---- Layer 2 ----
    k_layerM<<<gM, TB, 0, stream>>>((const uint*)act, (const int2*)nodeoff, col2,
                                    eps_s + 1, Wst + 1 * 8192, b1_s + 1 * 64,
                                    Wst + 1 * 8192 + 4096, b2_s + 1 * 64,
                                    hraw, parts + 2 * NSLICE * 128);

    // ---- Output (BN2 folded from partials) ----
    k_out<<<gN, TB, 0, stream>>>(hraw, parts + 2 * NSLICE * 128,
                                 gamma_s + 1 * 64, beta_s + 1 * 64, Wf, bf,
                                 (float*)d_out, N, invn);
}

// Round 19
// 392.123 us; speedup vs baseline: 1.1073x; 1.0069x over previous
//
#include <hip/hip_runtime.h>

#define N_NODES 100000
#define N_EDGES 3200000
#define BN_EPS 1e-5f

#define BLK_NODES 128            // nodes per bin block
#define NBLK 782                 // ceil(100000/128)
#define CHUNK 16384              // edges per fill workgroup (196 wgs; long runs
                                 // -> L2 write-combining; 4096 regressed 2x)
#define NW ((N_EDGES + CHUNK - 1) / CHUNK)  // 196
#define BCAP 4480                // words per bin (mean 4094, ~6 sigma)
#define CUR_PAD 16               // ints per cursor -> 64B
#define NSLICE 32                // stat partial slices

typedef unsigned int uint;
typedef unsigned short ushort;
typedef _Float16 half_t;
typedef __attribute__((ext_vector_type(8))) _Float16 h8v;  // 8 f16 (4 VGPRs)
typedef __attribute__((ext_vector_type(4))) float f4v;     // MFMA C/D

__device__ inline float bf_lo(uint u) { return __uint_as_float(u << 16); }
__device__ inline float bf_hi(uint u) { return __uint_as_float(u & 0xffff0000u); }
__device__ inline float h_lo(uint u) {
    union { ushort s; half_t h; } r; r.s = (ushort)(u & 0xffffu); return (float)r.h;
}
__device__ inline float h_hi(uint u) {
    union { ushort s; half_t h; } r; r.s = (ushort)(u >> 16); return (float)r.h;
}
__device__ inline ushort f2bf(float a) {
    uint ua = __float_as_uint(a); ua += 0x7fffu + ((ua >> 16) & 1u);
    return (ushort)(ua >> 16);
}
__device__ inline ushort f2h(float a) {
    union { half_t h; ushort u; } r;
    r.h = (half_t)a;
    return r.u;
}
__device__ inline uint packh2(float a, float b) {
    return (uint)f2h(a) | ((uint)f2h(b) << 16);
}
__device__ inline h8v loadH(const ushort* p) {
    union { uint4 q; h8v f; } r;
    r.q = *(const uint4*)p;
    return r.f;
}
__device__ inline h8v loadHh(const half_t* p) {
    union { uint4 q; h8v f; } r;
    r.q = *(const uint4*)p;
    return r.f;
}
__device__ inline f4v mfma16(h8v a, h8v b, f4v c) {
    return __builtin_amdgcn_mfma_f32_16x16x32_f16(a, b, c, 0, 0, 0);
}

// ---------------------------------------------------------------------------
// Build h0 [N,16] in f16: [x0, x1, emb[label][0..7], 0 x6].
// Block 0 additionally converts/transposes all weights to f16 (merged k_wcvt).
__global__ __launch_bounds__(256) void k_h0(const float* __restrict__ x,
                                            const int* __restrict__ lab,
                                            const float* __restrict__ emb,
                                            ushort* __restrict__ h0,
                                            const float* __restrict__ W1_0,
                                            const float* __restrict__ W2_0,
                                            const float* __restrict__ W1_s,
                                            const float* __restrict__ W2_s,
                                            ushort* __restrict__ W0t,
                                            ushort* __restrict__ W20t,
                                            ushort* __restrict__ Wst, int n) {
    int i = blockIdx.x * blockDim.x + threadIdx.x;
    if (i < n) {
        float v[16];
        v[0] = x[2 * i];
        v[1] = x[2 * i + 1];
        int L = lab[i];
#pragma unroll
        for (int k = 0; k < 8; k++) v[2 + k] = emb[L * 8 + k];
#pragma unroll
        for (int k = 10; k < 16; k++) v[k] = 0.f;
        uint o8[8];
#pragma unroll
        for (int k = 0; k < 8; k++) o8[k] = packh2(v[2 * k], v[2 * k + 1]);
        uint4* o = (uint4*)(h0 + (size_t)i * 16);
        o[0] = uint4{o8[0], o8[1], o8[2], o8[3]};
        o[1] = uint4{o8[4], o8[5], o8[6], o8[7]};
    }
    if (blockIdx.x == 0) {
        int t = threadIdx.x;
        for (int j = t; j < 64 * 32; j += 256) {       // W0t [64][32], K padded
            int nn = j >> 5, k = j & 31;
            W0t[j] = (k < 10) ? f2h(W1_0[k * 64 + nn]) : (ushort)0;
        }
        for (int j = t; j < 4096; j += 256) {          // W20t [64][64]
            int nn = j >> 6, k = j & 63;
            W20t[j] = f2h(W2_0[k * 64 + nn]);
        }
        for (int l = 0; l < 2; l++) {
            const float* w1 = W1_s + l * 4096;
            const float* w2 = W2_s + l * 4096;
            for (int j = t; j < 4096; j += 256) {
                int nn = j >> 6, k = j & 63;
                Wst[l * 8192 + j] = f2h(w1[k * 64 + nn]);
                Wst[l * 8192 + 4096 + j] = f2h(w2[k * 64 + nn]);
            }
        }
    }
}

// ---------------------------------------------------------------------------
// LDS-binned fill: count chunk into 782 bins, reserve contiguous runs
// (1 atomic per wg-bin), stream words into runs. CHUNK=16384: ~21-word runs
// assemble full lines in L2 (write amp ~2x); smaller chunks regress (r17).
__global__ __launch_bounds__(256) void k_fill(const int* __restrict__ src,
                                              const int* __restrict__ dst,
                                              int* __restrict__ gcur,
                                              int* __restrict__ bucket) {
    __shared__ int cnt[NBLK];
    __shared__ int off[NBLK];
    int t = threadIdx.x;
    for (int b = t; b < NBLK; b += 256) cnt[b] = 0;
    __syncthreads();
    int my0 = blockIdx.x * CHUNK + t * 64;
    for (int k = 0; k < 64; k += 4) {
        int e = my0 + k;
        if (e + 3 < N_EDGES) {
            int4 d4 = *(const int4*)(dst + e);
            atomicAdd(&cnt[d4.x >> 7], 1);
            atomicAdd(&cnt[d4.y >> 7], 1);
            atomicAdd(&cnt[d4.z >> 7], 1);
            atomicAdd(&cnt[d4.w >> 7], 1);
        } else {
#pragma unroll
            for (int kk = 0; kk < 4; kk++) {
                int ee = e + kk;
                if (ee < N_EDGES) atomicAdd(&cnt[dst[ee] >> 7], 1);
            }
        }
    }
    __syncthreads();
    for (int b = t; b < NBLK; b += 256) {
        int c = cnt[b];
        off[b] = (c > 0) ? atomicAdd(&gcur[b * CUR_PAD], c) : 0;
    }
    __syncthreads();
    for (int k = 0; k < 64; k += 4) {
        int e = my0 + k;
        if (e + 3 < N_EDGES) {
            int4 d4 = *(const int4*)(dst + e);
            int4 s4 = *(const int4*)(src + e);
            int dd[4] = {d4.x, d4.y, d4.z, d4.w};
            int ss[4] = {s4.x, s4.y, s4.z, s4.w};
#pragma unroll
            for (int kk = 0; kk < 4; kk++) {
                int b = dd[kk] >> 7;
                int p = atomicAdd(&off[b], 1);
                if (p < BCAP)
                    bucket[(size_t)b * BCAP + p] = ((dd[kk] & 127) << 17) | ss[kk];
            }
        } else {
#pragma unroll
            for (int kk = 0; kk < 4; kk++) {
                int ee = e + kk;
                if (ee < N_EDGES) {
                    int d = dst[ee], s = src[ee];
                    int b = d >> 7;
                    int p = atomicAdd(&off[b], 1);
                    if (p < BCAP)
                        bucket[(size_t)b * BCAP + p] = ((d & 127) << 17) | s;
                }
            }
        }
    }
}

// ---------------------------------------------------------------------------
// Per-block counting sort -> per-node-contiguous col2 + nodeoff = (start,deg)
__global__ __launch_bounds__(256) void k_sort(const int* __restrict__ gcur,
                                              const int* __restrict__ bucket,
                                              int* __restrict__ col2,
                                              int2* __restrict__ nodeoff, int n) {
    __shared__ int cnt[BLK_NODES];
    __shared__ int scn[BLK_NODES];
    __shared__ int cur[BLK_NODES];
    int t = threadIdx.x;
    int blk = blockIdx.x;
    if (t < BLK_NODES) cnt[t] = 0;
    __syncthreads();
    int cc = min(gcur[blk * CUR_PAD], BCAP);
    const int* bb = bucket + (size_t)blk * BCAP;
    for (int i = t; i < cc; i += 256) atomicAdd(&cnt[bb[i] >> 17], 1);
    __syncthreads();
    if (t < BLK_NODES) scn[t] = cnt[t];
    __syncthreads();
#pragma unroll
    for (int off = 1; off < BLK_NODES; off <<= 1) {
        int v = (t >= off && t < BLK_NODES) ? scn[t - off] : 0;
        __syncthreads();
        if (t < BLK_NODES) scn[t] += v;
        __syncthreads();
    }
    if (t < BLK_NODES) {
        int start = scn[t] - cnt[t];
        cur[t] = start;
        int node = blk * BLK_NODES + t;
        if (node < n) nodeoff[node] = int2{blk * BCAP + start, cnt[t]};
    }
    __syncthreads();
    int* out = col2 + (size_t)blk * BCAP;
    for (int i = t; i < cc; i += 256) {
        int w = bb[i];
        int p = atomicAdd(&cur[w >> 17], 1);
        out[p] = w & 0x1FFFF;
    }
}

// ---------------------------------------------------------------------------
// Layer 0: block = 4 waves = 64 nodes. Gather16 over f16 h0 (32B rows;
// 2 nodes/wave x 8 rounds, depth-2 col pipeline) into wave-private f16 LDS,
// then f16 MFMA MLP + stats + f16 store.
__global__ __launch_bounds__(256, 4) void k_layer0M(const ushort* __restrict__ h0,
                                                    const int2* __restrict__ nodeoff,
                                                    const int* __restrict__ col,
                                                    const float* __restrict__ epsp,
                                                    const ushort* __restrict__ W0t,
                                                    const float* __restrict__ b1,
                                                    const ushort* __restrict__ W20t,
                                                    const float* __restrict__ b2,
                                                    ushort* __restrict__ hraw,
                                                    float* __restrict__ part_out) {
    __shared__ half_t buf[4][16][72];   // comb (cols 0..31) then h1 (cols 0..63)
    int t = threadIdx.x, w = t >> 6, lane = t & 63;
    int base = blockIdx.x * 64 + w * 16;
    float ep = 1.f + *epsp;
    int hl = lane >> 5, l5 = lane & 31;
    int q = l5 & 3, g = l5 >> 2;  // 8 groups x 4 lanes per half
    const uint* hb = (const uint*)h0;  // row = 8 uints (16 f16)

    int nj = base + (lane & 15);
    int2 no2 = nodeoff[nj];  // padded past N
    int myStart = no2.x;
    int myDeg = (nj < N_NODES) ? no2.y : 0;

    int stC, dgC, mxC, wvC, wv2C;
    {
        stC = __shfl(myStart, hl, 64);
        dgC = __shfl(myDeg, hl, 64);
        int dA = __shfl(myDeg, 0, 64), dB = __shfl(myDeg, 1, 64);
        mxC = max(dA, dB);
        wvC = (dgC > 0) ? col[stC + min(l5, dgC - 1)] : 0;
        wv2C = (mxC > 32) ? ((dgC > 32) ? col[stC + min(32 + l5, dgC - 1)] : wvC) : 0;
    }

    for (int r = 0; r < 8; r++) {
        int stN = 0, dgN = 0, mxN = 0, wvN = 0, wv2N = 0;
        if (r < 7) {
            stN = __shfl(myStart, 2 * (r + 1) + hl, 64);
            dgN = __shfl(myDeg, 2 * (r + 1) + hl, 64);
            int dA = __shfl(myDeg, 2 * (r + 1), 64);
            int dB = __shfl(myDeg, 2 * (r + 1) + 1, 64);
            mxN = max(dA, dB);
            wvN = (dgN > 0) ? col[stN + min(l5, dgN - 1)] : 0;
            wv2N = (mxN > 32) ? ((dgN > 32) ? col[stN + min(32 + l5, dgN - 1)] : wvN) : 0;
        }
        int deg = dgC, mx = mxC;
        float ac[4] = {0.f, 0.f, 0.f, 0.f};
        if (mx > 0) {
            int idx[4];
#pragma unroll
            for (int i = 0; i < 4; i++) idx[i] = __shfl(wvC, (hl << 5) + g + 8 * i, 64);
            uint2 rows[4];
#pragma unroll
            for (int i = 0; i < 4; i++)
                rows[i] = *(const uint2*)(hb + (size_t)idx[i] * 8 + q * 2);
#pragma unroll
            for (int i = 0; i < 4; i++) {
                float m = (g + 8 * i < deg) ? 1.f : 0.f;
                ac[0] = fmaf(m, h_lo(rows[i].x), ac[0]);
                ac[1] = fmaf(m, h_hi(rows[i].x), ac[1]);
                ac[2] = fmaf(m, h_lo(rows[i].y), ac[2]);
                ac[3] = fmaf(m, h_hi(rows[i].y), ac[3]);
            }
            if (mx > 32) {
                int idx2[4];
#pragma unroll
                for (int i = 0; i < 4; i++) idx2[i] = __shfl(wv2C, (hl << 5) + g + 8 * i, 64);
                uint2 rows2[4];
#pragma unroll
                for (int i = 0; i < 4; i++)
                    rows2[i] = *(const uint2*)(hb + (size_t)idx2[i] * 8 + q * 2);
#pragma unroll
                for (int i = 0; i < 4; i++) {
                    float m = (32 + g + 8 * i < deg) ? 1.f : 0.f;
                    ac[0] = fmaf(m, h_lo(rows2[i].x), ac[0]);
                    ac[1] = fmaf(m, h_hi(rows2[i].x), ac[1]);
                    ac[2] = fmaf(m, h_lo(rows2[i].y), ac[2]);
                    ac[3] = fmaf(m, h_hi(rows2[i].y), ac[3]);
                }
                for (int e = 64 + g; e < deg; e += 8) {
                    uint2 v = *(const uint2*)(hb + (size_t)col[stC + e] * 8 + q * 2);
                    ac[0] += h_lo(v.x); ac[1] += h_hi(v.x);
                    ac[2] += h_lo(v.y); ac[3] += h_hi(v.y);
                }
            }
        }
#pragma unroll
        for (int o = 4; o < 32; o <<= 1) {
#pragma unroll
            for (int k = 0; k < 4; k++) ac[k] += __shfl_xor(ac[k], o, 64);
        }
        int node = base + 2 * r + hl;
        bool valid = node < N_NODES;
        int nodeC = valid ? node : 0;
        float vm = valid ? ep : 0.f;
        uint2 sv = *(const uint2*)(hb + (size_t)nodeC * 8 + q * 2);
        ac[0] = fmaf(vm, h_lo(sv.x), ac[0]);
        ac[1] = fmaf(vm, h_hi(sv.x), ac[1]);
        ac[2] = fmaf(vm, h_lo(sv.y), ac[2]);
        ac[3] = fmaf(vm, h_hi(sv.y), ac[3]);
        if (!valid) { ac[0] = ac[1] = ac[2] = ac[3] = 0.f; }
        if (g == 0) {
            int nl = 2 * r + hl;
            *(uint2*)&buf[w][nl][q * 4] = uint2{packh2(ac[0], ac[1]), packh2(ac[2], ac[3])};
            *(uint2*)&buf[w][nl][16 + q * 4] = uint2{0u, 0u};
        }
        stC = stN; dgC = dgN; mxC = mxN; wvC = wvN; wv2C = wv2N;
    }
    // ---- f16 MFMA MLP (wave-synchronous LDS; no barrier; buf aliased) ----
    int mr = lane & 15, kq = lane >> 4, nc = lane & 15;
    h8v A0 = loadHh(&buf[w][mr][kq * 8]);
#pragma unroll
    for (int nt = 0; nt < 4; nt++) {
        float bb = b1[nt * 16 + nc];
        f4v c = {bb, bb, bb, bb};
        c = mfma16(A0, loadH(W0t + (nt * 16 + nc) * 32 + kq * 8), c);
#pragma unroll
        for (int r2 = 0; r2 < 4; r2++)
            buf[w][kq * 4 + r2][nt * 16 + nc] = (half_t)fmaxf(c[r2], 0.f);
    }
    h8v P0 = loadHh(&buf[w][mr][kq * 8]);
    h8v P1 = loadHh(&buf[w][mr][32 + kq * 8]);
    float sA[4], sB[4];
#pragma unroll
    for (int nt = 0; nt < 4; nt++) { sA[nt] = 0.f; sB[nt] = 0.f; }
#pragma unroll
    for (int nt = 0; nt < 4; nt++) {
        float bb = b2[nt * 16 + nc];
        f4v c = {bb, bb, bb, bb};
        c = mfma16(P0, loadH(W20t + (nt * 16 + nc) * 64 + kq * 8), c);
        c = mfma16(P1, loadH(W20t + (nt * 16 + nc) * 64 + 32 + kq * 8), c);
#pragma unroll
        for (int r2 = 0; r2 < 4; r2++) {
            int node = base + kq * 4 + r2;
            float vv = fmaxf(c[r2], 0.f);
            if (node < N_NODES) {
                sA[nt] += vv;
                sB[nt] = fmaf(vv, vv, sB[nt]);
                hraw[(size_t)node * 64 + nt * 16 + nc] = f2h(vv);
            }
        }
    }
#pragma unroll
    for (int o = 16; o < 64; o <<= 1) {
#pragma unroll
        for (int nt = 0; nt < 4; nt++) {
            sA[nt] += __shfl_xor(sA[nt], o, 64);
            sB[nt] += __shfl_xor(sB[nt], o, 64);
        }
    }
    if (kq == 0) {
        float* pp = part_out + (blockIdx.x & (NSLICE - 1)) * 128;
#pragma unroll
        for (int nt = 0; nt < 4; nt++) {
            atomicAdd(&pp[nt * 16 + nc], sA[nt]);
            atomicAdd(&pp[64 + nt * 16 + nc], sB[nt]);
        }
    }
}

// ---------------------------------------------------------------------------
// Activation pass: act = bf16(relu(h*sc+sh)), h stored f16, BN from partials.
__global__ __launch_bounds__(256) void k_act(const ushort* __restrict__ hraw,
                                             const float* __restrict__ part,
                                             const float* __restrict__ gamma,
                                             const float* __restrict__ beta,
                                             ushort* __restrict__ act, float invn) {
    __shared__ float st[128];
    __shared__ float sc[64], sh[64];
    int t = threadIdx.x;
    if (t < 128) {
        float S = 0.f;
#pragma unroll 8
        for (int s = 0; s < NSLICE; s++) S += part[s * 128 + t];
        st[t] = S;
    }
    __syncthreads();
    if (t < 64) {
        float mu = st[t] * invn;
        float var = fmaxf(st[64 + t] * invn - mu * mu, 0.f);
        float s = gamma[t] * rsqrtf(var + BN_EPS);
        sc[t] = s;
        sh[t] = beta[t] - mu * s;
    }
    __syncthreads();
    int base = (blockIdx.x * 256 + t) * 4;
    int f0 = base & 63;
    uint2 hv = *(const uint2*)(hraw + base);
    float a0 = fmaxf(fmaf(h_lo(hv.x), sc[f0 + 0], sh[f0 + 0]), 0.f);
    float a1 = fmaxf(fmaf(h_hi(hv.x), sc[f0 + 1], sh[f0 + 1]), 0.f);
    float a2 = fmaxf(fmaf(h_lo(hv.y), sc[f0 + 2], sh[f0 + 2]), 0.f);
    float a3 = fmaxf(fmaf(h_hi(hv.y), sc[f0 + 3], sh[f0 + 3]), 0.f);
    uint2 o;
    o.x = (uint)f2bf(a0) | ((uint)f2bf(a1) << 16);
    o.y = (uint)f2bf(a2) | ((uint)f2bf(a3) << 16);
    *(uint2*)(act + base) = o;
}

// ---------------------------------------------------------------------------
// Layers 1/2: block = 4 waves = 64 nodes. Gather64 over pre-activated bf16
// (2 nodes/wave x 8 rounds, depth-2 col pipeline) into wave-private f16 LDS,
// then f16 MFMA MLP + stats + f16 store.
__global__ __launch_bounds__(256, 4) void k_layerM(const uint* __restrict__ actin,
                                                   const int2* __restrict__ nodeoff,
                                                   const int* __restrict__ col,
                                                   const float* __restrict__ epsp,
                                                   const ushort* __restrict__ W1t,
                                                   const float* __restrict__ b1,
                                                   const ushort* __restrict__ W2t,
                                                   const float* __restrict__ b2,
                                                   ushort* __restrict__ hraw,
                                                   float* __restrict__ part_out) {
    __shared__ half_t buf[4][16][72];   // comb then h1 (aliased, wave-private)
    int t = threadIdx.x, w = t >> 6, lane = t & 63;
    int base = blockIdx.x * 64 + w * 16;
    float ep = 1.f + *epsp;
    int hl = lane >> 5, l5 = lane & 31;
    int q = l5 & 7, g = l5 >> 3;  // 4 groups x 8 lanes per half
    const uint4* hb4 = (const uint4*)actin;

    int nj = base + (lane & 15);
    int2 no2 = nodeoff[nj];
    int myStart = no2.x;
    int myDeg = (nj < N_NODES) ? no2.y : 0;

    int stC, dgC, mxC, wvC, wv2C;
    {
        stC = __shfl(myStart, hl, 64);
        dgC = __shfl(myDeg, hl, 64);
        int dA = __shfl(myDeg, 0, 64), dB = __shfl(myDeg, 1, 64);
        mxC = max(dA, dB);
        wvC = (dgC > 0) ? col[stC + min(l5, dgC - 1)] : 0;
        wv2C = (mxC > 32) ? ((dgC > 32) ? col[stC + min(32 + l5, dgC - 1)] : wvC) : 0;
    }

    for (int r = 0; r < 8; r++) {
        int stN = 0, dgN = 0, mxN = 0, wvN = 0, wv2N = 0;
        if (r < 7) {
            stN = __shfl(myStart, 2 * (r + 1) + hl, 64);
            dgN = __shfl(myDeg, 2 * (r + 1) + hl, 64);
            int dA = __shfl(myDeg, 2 * (r + 1), 64);
            int dB = __shfl(myDeg, 2 * (r + 1) + 1, 64);
            mxN = max(dA, dB);
            wvN = (dgN > 0) ? col[stN + min(l5, dgN - 1)] : 0;
            wv2N = (mxN > 32) ? ((dgN > 32) ? col[stN + min(32 + l5, dgN - 1)] : wvN) : 0;
        }
        int deg = dgC, mx = mxC;
        float acc[8];
#pragma unroll
        for (int k = 0; k < 8; k++) acc[k] = 0.f;
        auto procm = [&](uint4 v, float m) {
            acc[0] = fmaf(m, bf_lo(v.x), acc[0]);
            acc[1] = fmaf(m, bf_hi(v.x), acc[1]);
            acc[2] = fmaf(m, bf_lo(v.y), acc[2]);
            acc[3] = fmaf(m, bf_hi(v.y), acc[3]);
            acc[4] = fmaf(m, bf_lo(v.z), acc[4]);
            acc[5] = fmaf(m, bf_hi(v.z), acc[5]);
            acc[6] = fmaf(m, bf_lo(v.w), acc[6]);
            acc[7] = fmaf(m, bf_hi(v.w), acc[7]);
        };
        if (mx > 0) {
            int idx[8];
#pragma unroll
            for (int i = 0; i < 8; i++) idx[i] = __shfl(wvC, (hl << 5) + g + 4 * i, 64);
            uint4 rows[8];
#pragma unroll
            for (int i = 0; i < 8; i++) rows[i] = hb4[(size_t)idx[i] * 8 + q];
#pragma unroll
            for (int i = 0; i < 8; i++) procm(rows[i], (g + 4 * i < deg) ? 1.f : 0.f);
            if (mx > 32) {
                int idx2[8];
#pragma unroll
                for (int i = 0; i < 8; i++) idx2[i] = __shfl(wv2C, (hl << 5) + g + 4 * i, 64);
                uint4 rows2[8];
#pragma unroll
                for (int i = 0; i < 8; i++) rows2[i] = hb4[(size_t)idx2[i] * 8 + q];
#pragma unroll
                for (int i = 0; i < 8; i++) procm(rows2[i], (32 + g + 4 * i < deg) ? 1.f : 0.f);
                for (int e = 64 + g; e < deg; e += 4)
                    procm(hb4[(size_t)col[stC + e] * 8 + q], 1.f);
            }
        }
#pragma unroll
        for (int o = 8; o < 32; o <<= 1) {
#pragma unroll
            for (int k = 0; k < 8; k++) acc[k] += __shfl_xor(acc[k], o, 64);
        }
        int node = base + 2 * r + hl;
        bool valid = node < N_NODES;
        int nodeC = valid ? node : 0;
        float vm = valid ? ep : 0.f;
        uint4 v = hb4[(size_t)nodeC * 8 + q];
        acc[0] = fmaf(vm, bf_lo(v.x), acc[0]);
        acc[1] = fmaf(vm, bf_hi(v.x), acc[1]);
        acc[2] = fmaf(vm, bf_lo(v.y), acc[2]);
        acc[3] = fmaf(vm, bf_hi(v.y), acc[3]);
        acc[4] = fmaf(vm, bf_lo(v.z), acc[4]);
        acc[5] = fmaf(vm, bf_hi(v.z), acc[5]);
        acc[6] = fmaf(vm, bf_lo(v.w), acc[6]);
        acc[7] = fmaf(vm, bf_hi(v.w), acc[7]);
        if (!valid) {
#pragma unroll
            for (int k = 0; k < 8; k++) acc[k] = 0.f;
        }
        if (g == 0) {
            int nl = 2 * r + hl;
            *(uint2*)&buf[w][nl][q * 8 + 0] = uint2{packh2(acc[0], acc[1]), packh2(acc[2], acc[3])};
            *(uint2*)&buf[w][nl][q * 8 + 4] = uint2{packh2(acc[4], acc[5]), packh2(acc[6], acc[7])};
        }
        stC = stN; dgC = dgN; mxC = mxN; wvC = wvN; wv2C = wv2N;
    }
    // ---- f16 MFMA MLP (wave-synchronous LDS; no barrier; buf aliased) ----
    int mr = lane & 15, kq = lane >> 4, nc = lane & 15;
    h8v A0 = loadHh(&buf[w][mr][kq * 8]);
    h8v A1 = loadHh(&buf[w][mr][32 + kq * 8]);
#pragma unroll
    for (int nt = 0; nt < 4; nt++) {
        float bb = b1[nt * 16 + nc];
        f4v c = {bb, bb, bb, bb};
        c = mfma16(A0, loadH(W1t + (nt * 16 + nc) * 64 + kq * 8), c);
        c = mfma16(A1, loadH(W1t + (nt * 16 + nc) * 64 + 32 + kq * 8), c);
#pragma unroll
        for (int r2 = 0; r2 < 4; r2++)
            buf[w][kq * 4 + r2][nt * 16 + nc] = (half_t)fmaxf(c[r2], 0.f);
    }
    h8v P0 = loadHh(&buf[w][mr][kq * 8]);
    h8v P1 = loadHh(&buf[w][mr][32 + kq * 8]);
    float sA[4], sB[4];
#pragma unroll
    for (int nt = 0; nt < 4; nt++) { sA[nt] = 0.f; sB[nt] = 0.f; }
#pragma unroll
    for (int nt = 0; nt < 4; nt++) {
        float bb = b2[nt * 16 + nc];
        f4v c = {bb, bb, bb, bb};
        c = mfma16(P0, loadH(W2t + (nt * 16 + nc) * 64 + kq * 8), c);
        c = mfma16(P1, loadH(W2t + (nt * 16 + nc) * 64 + 32 + kq * 8), c);
#pragma unroll
        for (int r2 = 0; r2 < 4; r2++) {
            int node = base + kq * 4 + r2;
            float vv = fmaxf(c[r2], 0.f);
            if (node < N_NODES) {
                sA[nt] += vv;
                sB[nt] = fmaf(vv, vv, sB[nt]);
                hraw[(size_t)node * 64 + nt * 16 + nc] = f2h(vv);
            }
        }
    }
#pragma unroll
    for (int o = 16; o < 64; o <<= 1) {
#pragma unroll
        for (int nt = 0; nt < 4; nt++) {
            sA[nt] += __shfl_xor(sA[nt], o, 64);
            sB[nt] += __shfl_xor(sB[nt], o, 64);
        }
    }
    if (kq == 0) {
        float* pp = part_out + (blockIdx.x & (NSLICE - 1)) * 128;
#pragma unroll
        for (int nt = 0; nt < 4; nt++) {
            atomicAdd(&pp[nt * 16 + nc], sA[nt]);
            atomicAdd(&pp[64 + nt * 16 + nc], sB[nt]);
        }
    }
}

// ---------------------------------------------------------------------------
// Final: fold BN2 partials; out[i] = bf + sum_j relu(h*sc+sh) * Wf[j]
__global__ __launch_bounds__(256) void k_out(const ushort* __restrict__ hraw,
                                             const float* __restrict__ part,
                                             const float* __restrict__ gamma,
                                             const float* __restrict__ beta,
                                             const float* __restrict__ Wf,
                                             const float* __restrict__ bfp,
                                             float* __restrict__ out, int n,
                                             float invn) {
    __shared__ float st[128];
    __shared__ float sc[64], sh[64];
    int t = threadIdx.x;
    if (t < 128) {
        float S = 0.f;
#pragma unroll 8
        for (int s = 0; s < NSLICE; s++) S += part[s * 128 + t];
        st[t] = S;
    }
    __syncthreads();
    if (t < 64) {
        float mu = st[t] * invn;
        float var = fmaxf(st[64 + t] * invn - mu * mu, 0.f);
        float s = gamma[t] * rsqrtf(var + BN_EPS);
        sc[t] = s;
        sh[t] = beta[t] - mu * s;
    }
    __syncthreads();
    int i = blockIdx.x * blockDim.x + threadIdx.x;
    if (i >= n) return;
    float acc = *bfp;
    const uint2* h2 = (const uint2*)(hraw + (size_t)i * 64);
#pragma unroll
    for (int qq = 0; qq < 16; qq++) {
        uint2 v = h2[qq];
        int j = qq * 4;
        acc = fmaf(fmaxf(fmaf(h_lo(v.x), sc[j + 0], sh[j + 0]), 0.f), Wf[j + 0], acc);
        acc = fmaf(fmaxf(fmaf(h_hi(v.x), sc[j + 1], sh[j + 1]), 0.f), Wf[j + 1], acc);
        acc = fmaf(fmaxf(fmaf(h_lo(v.y), sc[j + 2], sh[j + 2]), 0.f), Wf[j + 2], acc);
        acc = fmaf(fmaxf(fmaf(h_hi(v.y), sc[j + 3], sh[j + 3]), 0.f), Wf[j + 3], acc);
    }
    out[i] = acc;
}

// ---------------------------------------------------------------------------
extern "C" void kernel_launch(void* const* d_in, const int* in_sizes, int n_in,
                              void* d_out, int out_size, void* d_ws, size_t ws_size,
                              hipStream_t stream) {
    const float* x      = (const float*)d_in[0];
    const int*   lab    = (const int*)d_in[1];
    const int*   edge   = (const int*)d_in[2];  // [2][E]: src then dst
    const float* emb    = (const float*)d_in[3];
    const float* W1_0   = (const float*)d_in[4];
    const float* b1_0   = (const float*)d_in[5];
    const float* W2_0   = (const float*)d_in[6];
    const float* b2_0   = (const float*)d_in[7];
    const float* eps_0  = (const float*)d_in[8];
    const float* gamma_0= (const float*)d_in[9];
    const float* beta_0 = (const float*)d_in[10];
    const float* W1_s   = (const float*)d_in[11];
    const float* b1_s   = (const float*)d_in[12];
    const float* W2_s   = (const float*)d_in[13];
    const float* b2_s   = (const float*)d_in[14];
    const float* eps_s  = (const float*)d_in[15];
    const float* gamma_s= (const float*)d_in[16];
    const float* beta_s = (const float*)d_in[17];
    const float* Wf     = (const float*)d_in[18];
    const float* bf     = (const float*)d_in[19];

    const int N = N_NODES, E = N_EDGES;
    const int* srcp = edge;
    const int* dstp = edge + E;

    char* p = (char*)d_ws;
    auto alloc = [&](size_t bytes) {
        void* r = (void*)p;
        p += (bytes + 255) & ~(size_t)255;
        return r;
    };
    int* bucket  = (int*)alloc((size_t)NBLK * BCAP * 4);      // 14.0 MB
    int* col2    = (int*)alloc((size_t)NBLK * BCAP * 4);      // 14.0 MB
    int* gcur    = (int*)alloc((size_t)NBLK * CUR_PAD * 4);   // 50 KB
    int* nodeoff = (int*)alloc((size_t)(N + 64) * 8);         // padded for OOB reads
    ushort* hraw = (ushort*)alloc((size_t)N * 64 * 2);        // 12.8 MB (f16)
    ushort* act  = (ushort*)alloc((size_t)N * 64 * 2);        // 12.8 MB (bf16)
    ushort* h0   = (ushort*)alloc((size_t)N * 16 * 2);        //  3.2 MB (f16)
    float* parts = (float*)alloc(3 * NSLICE * 128 * 4);       // 48 KB
    ushort* W0t  = (ushort*)alloc(64 * 32 * 2);
    ushort* W20t = (ushort*)alloc(4096 * 2);
    ushort* Wst  = (ushort*)alloc(2 * 8192 * 2);

    hipMemsetAsync(gcur, 0, (size_t)NBLK * CUR_PAD * 4, stream);
    hipMemsetAsync(parts, 0, 3 * NSLICE * 128 * 4, stream);

    const int TB = 256;
    const int gN = (N + TB - 1) / TB;
    const int gM = (N + 63) / 64;  // 1563 blocks, 64 nodes each
    const int gA = N * 64 / 1024;
    const float invn = 1.0f / (float)N;

    k_h0<<<gN, TB, 0, stream>>>(x, lab, emb, h0, W1_0, W2_0, W1_s, W2_s,
                                W0t, W20t, Wst, N);
    k_fill<<<NW, TB, 0, stream>>>(srcp, dstp, gcur, bucket);
    k_sort<<<NBLK, TB, 0, stream>>>(gcur, bucket, col2, (int2*)nodeoff, N);

    // ---- Layer 0 ----
    k_layer0M<<<gM, TB, 0, stream>>>(h0, (const int2*)nodeoff, col2, eps_0, W0t,
                                     b1_0, W20t, b2_0, hraw,
                                     parts + 0 * NSLICE * 128);
    k_act<<<gA, TB, 0, stream>>>(hraw, parts + 0 * NSLICE * 128, gamma_0, beta_0,
                                 act, invn);

    // ---- Layer 1 ----
    k_layerM<<<gM, TB, 0, stream>>>((const uint*)act, (const int2*)nodeoff, col2,
                                    eps_s + 0, Wst + 0 * 8192, b1_s + 0 * 64,
                                    Wst + 0 * 8192 + 4096, b2_s + 0 * 64,
                                    hraw, parts + 1 * NSLICE * 128);
    k_act<<<gA, TB, 0, stream>>>(hraw, parts + 1 * NSLICE * 128, gamma_s + 0 * 64,
                                 beta_s + 0 * 64, act, invn);

    // ---- Layer 2 ----
    k_layerM<<<gM, TB, 0, stream>>>((const uint*)act, (const int2*)nodeoff, col2,
                                    eps_s + 1, Wst + 1 * 8192, b1_s + 1 * 64,
                                    Wst + 1 * 8192 + 4096, b2_s + 1 * 64,
                                    hraw, parts + 2 * NSLICE * 128);

    // ---- Output (BN2 folded from partials) ----
    k_out<<<gN, TB, 0, stream>>>(hraw, parts + 2 * NSLICE * 128,
                                 gamma_s + 1 * 64, beta_s + 1 * 64, Wf, bf,
                                 (float*)d_out, N, invn);
}